// Round 6
// baseline (508.261 us; speedup 1.0000x reference)
//
#include <hip/hip_runtime.h>
#include <math.h>

#define N_NODES 100000
#define N_EDGES 1600000
#define IN_DIM 64
#define HID 128
#define OUT_DIM 2
#define N_GRAPHS 64

#define SCAN_BLOCKS ((N_NODES + 255) / 256)  // 391
#define E4 (N_EDGES / 4)                     // 400000

typedef unsigned int uint32;

static __device__ __forceinline__ ushort f2bf(float f) {
    uint32 u = __float_as_uint(f);
    uint32 r = (u + 0x7fff + ((u >> 16) & 1)) >> 16;  // RNE
    return (ushort)r;
}
static __device__ __forceinline__ float bf2f(uint32 u) {
    return __uint_as_float(u << 16);
}
static __device__ __forceinline__ float bflo(uint32 u) { return bf2f(u & 0xffffu); }
static __device__ __forceinline__ float bfhi(uint32 u) { return bf2f(u >> 16); }

// ---------------- degree (4 edges/thread, fire-and-forget atomics) ----------------
__global__ __launch_bounds__(256) void k_deg_accum(const int4* __restrict__ dst4,
                                                   int* __restrict__ deg) {
    int i = blockIdx.x * 256 + threadIdx.x;
    if (i >= E4) return;
    int4 d = dst4[i];
    atomicAdd(&deg[d.x], 1);
    atomicAdd(&deg[d.y], 1);
    atomicAdd(&deg[d.z], 1);
    atomicAdd(&deg[d.w], 1);
}

// ---------------- CSR build: 3-phase scan ----------------
__global__ __launch_bounds__(256) void k_scan_part(const int* __restrict__ deg,
                                                   int* __restrict__ bsum) {
    __shared__ int red[256];
    int i = blockIdx.x * 256 + threadIdx.x;
    red[threadIdx.x] = (i < N_NODES) ? deg[i] : 0;
    __syncthreads();
    for (int off = 128; off > 0; off >>= 1) {
        if (threadIdx.x < off) red[threadIdx.x] += red[threadIdx.x + off];
        __syncthreads();
    }
    if (threadIdx.x == 0) bsum[blockIdx.x] = red[0];
}

__global__ __launch_bounds__(512) void k_scan_top(const int* __restrict__ bsum,
                                                  int* __restrict__ boff) {
    __shared__ int s[512];
    int t = threadIdx.x;
    s[t] = (t < SCAN_BLOCKS) ? bsum[t] : 0;
    __syncthreads();
    for (int off = 1; off < 512; off <<= 1) {
        int v = (t >= off) ? s[t - off] : 0;
        __syncthreads();
        s[t] += v;
        __syncthreads();
    }
    if (t < SCAN_BLOCKS) boff[t] = (t == 0) ? 0 : s[t - 1];
}

__global__ __launch_bounds__(256) void k_scan_write(const int* __restrict__ deg,
                                                    const int* __restrict__ boff,
                                                    int* __restrict__ row_start,
                                                    int* __restrict__ cursor,
                                                    float* __restrict__ dinv) {
    __shared__ int s[256];
    int t = threadIdx.x;
    int i = blockIdx.x * 256 + t;
    int v = (i < N_NODES) ? deg[i] : 0;
    s[t] = v;
    __syncthreads();
    for (int off = 1; off < 256; off <<= 1) {
        int u = (t >= off) ? s[t - off] : 0;
        __syncthreads();
        s[t] += u;
        __syncthreads();
    }
    if (i < N_NODES) {
        int base = boff[blockIdx.x];
        int excl = base + s[t] - v;
        row_start[i] = excl;
        cursor[i] = excl;
        dinv[i] = rsqrtf((float)(v + 1));  // +1 self loop
        if (i == N_NODES - 1) row_start[N_NODES] = base + s[t];
    }
}

// ---------------- scatter (4 edges/thread, 4 atomics in flight) ----------------
__global__ __launch_bounds__(256) void k_scatter(const int4* __restrict__ src4,
                                                 const int4* __restrict__ dst4,
                                                 int* __restrict__ cursor,
                                                 int* __restrict__ csr) {
    int i = blockIdx.x * 256 + threadIdx.x;
    if (i >= E4) return;
    int4 d = dst4[i];
    int4 s = src4[i];
    int p0 = atomicAdd(&cursor[d.x], 1);
    int p1 = atomicAdd(&cursor[d.y], 1);
    int p2 = atomicAdd(&cursor[d.z], 1);
    int p3 = atomicAdd(&cursor[d.w], 1);
    csr[p0] = s.x;
    csr[p1] = s.y;
    csr[p2] = s.z;
    csr[p3] = s.w;
}

// ---------------- pre-scale x by dinv -> bf16 ----------------
__global__ __launch_bounds__(256) void k_xscale(const float* __restrict__ x,
                                                const float* __restrict__ dinv,
                                                ushort* __restrict__ xs) {
    int idx = blockIdx.x * 256 + threadIdx.x;
    if (idx >= N_NODES * 16) return;
    float d = dinv[idx >> 4];
    float4 v = ((const float4*)x)[idx];
    ushort4 o;
    o.x = f2bf(v.x * d);
    o.y = f2bf(v.y * d);
    o.z = f2bf(v.z * d);
    o.w = f2bf(v.w * d);
    ((ushort4*)xs)[idx] = o;
}

// ---------------- aggregation (gather, CSR, bf16 rows, MLP-unrolled) ----------------
__global__ __launch_bounds__(256) void k_agg1(const int* __restrict__ row_start,
                                              const int* __restrict__ csr,
                                              const uint32* __restrict__ xs,
                                              const float* __restrict__ dinv,
                                              float* __restrict__ out) {
    int d = blockIdx.x * 8 + (threadIdx.x >> 5);
    int l = threadIdx.x & 31;
    float dd = dinv[d];
    uint32 u = xs[(long long)d * 32 + l];
    float a0 = bflo(u), a1 = bfhi(u);
    int e = row_start[d];
    int eend = row_start[d + 1];
    for (; e + 3 < eend; e += 4) {
        int s0 = csr[e], s1 = csr[e + 1], s2 = csr[e + 2], s3 = csr[e + 3];
        uint32 w0 = xs[(long long)s0 * 32 + l];
        uint32 w1 = xs[(long long)s1 * 32 + l];
        uint32 w2 = xs[(long long)s2 * 32 + l];
        uint32 w3 = xs[(long long)s3 * 32 + l];
        a0 += bflo(w0) + bflo(w1) + bflo(w2) + bflo(w3);
        a1 += bfhi(w0) + bfhi(w1) + bfhi(w2) + bfhi(w3);
    }
    for (; e < eend; ++e) {
        uint32 w = xs[(long long)csr[e] * 32 + l];
        a0 += bflo(w);
        a1 += bfhi(w);
    }
    float2 o;
    o.x = a0 * dd;
    o.y = a1 * dd;
    ((float2*)out)[(long long)d * 32 + l] = o;
}

__global__ __launch_bounds__(256) void k_agg2(const int* __restrict__ row_start,
                                              const int* __restrict__ csr,
                                              const uint2* __restrict__ hs,
                                              const float* __restrict__ dinv,
                                              float* __restrict__ out) {
    int d = blockIdx.x * 8 + (threadIdx.x >> 5);
    int l = threadIdx.x & 31;
    float dd = dinv[d];
    uint2 u = hs[(long long)d * 32 + l];
    float a0 = bflo(u.x), a1 = bfhi(u.x), a2 = bflo(u.y), a3 = bfhi(u.y);
    int e = row_start[d];
    int eend = row_start[d + 1];
    for (; e + 3 < eend; e += 4) {
        int s0 = csr[e], s1 = csr[e + 1], s2 = csr[e + 2], s3 = csr[e + 3];
        uint2 w0 = hs[(long long)s0 * 32 + l];
        uint2 w1 = hs[(long long)s1 * 32 + l];
        uint2 w2 = hs[(long long)s2 * 32 + l];
        uint2 w3 = hs[(long long)s3 * 32 + l];
        a0 += bflo(w0.x) + bflo(w1.x) + bflo(w2.x) + bflo(w3.x);
        a1 += bfhi(w0.x) + bfhi(w1.x) + bfhi(w2.x) + bfhi(w3.x);
        a2 += bflo(w0.y) + bflo(w1.y) + bflo(w2.y) + bflo(w3.y);
        a3 += bfhi(w0.y) + bfhi(w1.y) + bfhi(w2.y) + bfhi(w3.y);
    }
    for (; e < eend; ++e) {
        uint2 w = hs[(long long)csr[e] * 32 + l];
        a0 += bflo(w.x);
        a1 += bfhi(w.x);
        a2 += bflo(w.y);
        a3 += bfhi(w.y);
    }
    float4 o;
    o.x = a0 * dd;
    o.y = a1 * dd;
    o.z = a2 * dd;
    o.w = a3 * dd;
    ((float4*)out)[(long long)d * 32 + l] = o;
}

// ---------------- fused GEMM: out[N,HID] = relu(in[N,K] @ W + b) ----------------
template <int K, int OUT_BF>
__global__ __launch_bounds__(256) void k_gemm8(const float* __restrict__ in,
                                               const float* __restrict__ W,
                                               const float* __restrict__ bias,
                                               const float* __restrict__ dinv,
                                               void* __restrict__ outv) {
    __shared__ float xT[K * 8];
    int row0 = blockIdx.x * 8;
    int tid = threadIdx.x;
    for (int i = tid; i < 8 * K; i += 256) {
        int r = i / K, k = i % K;
        xT[k * 8 + r] = in[(long long)(row0 + r) * K + k];
    }
    __syncthreads();
    int j = tid & 127;
    int rh = tid >> 7;
    float a0 = 0.f, a1 = 0.f, a2 = 0.f, a3 = 0.f;
#pragma unroll 8
    for (int k = 0; k < K; ++k) {
        float w = W[k * HID + j];
        float4 xv = *(const float4*)&xT[k * 8 + rh * 4];
        a0 += w * xv.x;
        a1 += w * xv.y;
        a2 += w * xv.z;
        a3 += w * xv.w;
    }
    float b = bias[j];
    float acc[4] = {a0, a1, a2, a3};
#pragma unroll
    for (int r = 0; r < 4; ++r) {
        int row = row0 + rh * 4 + r;
        float v = acc[r] + b;
        v = v > 0.f ? v : 0.f;
        if (OUT_BF) {
            ((ushort*)outv)[(long long)row * HID + j] = f2bf(v * dinv[row]);
        } else {
            ((float*)outv)[(long long)row * HID + j] = v;
        }
    }
}

// ---------------- pooling ----------------
#define POOL_CHUNK 256
__global__ void k_pool(const float* __restrict__ h, const int* __restrict__ batch,
                       float* __restrict__ pooled, float* __restrict__ cnt) {
    int n0 = blockIdx.x * POOL_CHUNK;
    int n1 = n0 + POOL_CHUNK;
    if (n1 > N_NODES) n1 = N_NODES;
    if (n0 >= N_NODES) return;
    int j = threadIdx.x;  // 0..127
    float acc = 0.f;
    int cur = batch[n0];
    int c_local = 0;
    for (int n = n0; n < n1; ++n) {
        int g = batch[n];
        if (g != cur) {
            atomicAdd(&pooled[cur * HID + j], acc);
            if (j == 0) atomicAdd(&cnt[cur], (float)c_local);
            acc = 0.f;
            c_local = 0;
            cur = g;
        }
        acc += h[(long long)n * HID + j];
        ++c_local;
    }
    atomicAdd(&pooled[cur * HID + j], acc);
    if (j == 0) atomicAdd(&cnt[cur], (float)c_local);
}

// ---------------- head ----------------
__global__ void k_head(const float* __restrict__ pooled, const float* __restrict__ cnt,
                       const float* __restrict__ Wfc, const float* __restrict__ bfc,
                       float* __restrict__ out) {
    int g = threadIdx.x;
    if (g >= N_GRAPHS) return;
    float inv = 1.0f / fmaxf(cnt[g], 1.0f);
    float l0 = bfc[0], l1 = bfc[1];
    for (int j = 0; j < HID; ++j) {
        float p = pooled[g * HID + j] * inv;
        l0 += p * Wfc[j * OUT_DIM + 0];
        l1 += p * Wfc[j * OUT_DIM + 1];
    }
    float m = fmaxf(l0, l1);
    float lse = m + logf(expf(l0 - m) + expf(l1 - m));
    out[g * OUT_DIM + 0] = l0 - lse;
    out[g * OUT_DIM + 1] = l1 - lse;
}

extern "C" void kernel_launch(void* const* d_in, const int* in_sizes, int n_in,
                              void* d_out, int out_size, void* d_ws, size_t ws_size,
                              hipStream_t stream) {
    const float* x   = (const float*)d_in[0];
    const float* W1  = (const float*)d_in[1];
    const float* b1  = (const float*)d_in[2];
    const float* W2  = (const float*)d_in[3];
    const float* b2  = (const float*)d_in[4];
    const float* Wfc = (const float*)d_in[5];
    const float* bfc = (const float*)d_in[6];
    const int* ei    = (const int*)d_in[7];   // [2, E]
    const int* batch = (const int*)d_in[8];
    const int* src = ei;
    const int* dst = ei + N_EDGES;
    float* out = (float*)d_out;

    // workspace layout
    float* bufA = (float*)d_ws;                    // N*128 f32
    float* bufB = bufA + (long long)N_NODES * HID; // N*128 f32; start doubles as xs/hs bf16
    ushort* xs = (ushort*)bufB;                    // N*64 bf16
    ushort* hs = (ushort*)bufB;                    // N*128 bf16
    int* row_start = (int*)(bufB + (long long)N_NODES * HID);  // N+1
    int* cursor = row_start + (N_NODES + 1);       // N
    int* deg = cursor + N_NODES;                   // N
    float* dinv = (float*)(deg + N_NODES);         // N
    int* bsum = (int*)(dinv + N_NODES);            // SCAN_BLOCKS
    int* boff = bsum + SCAN_BLOCKS;                // SCAN_BLOCKS
    int* csr = boff + SCAN_BLOCKS;                 // E
    float* pooled = (float*)(csr + N_EDGES);       // G*HID
    float* cnt = pooled + N_GRAPHS * HID;          // G

    // degree + CSR
    hipMemsetAsync(deg, 0, N_NODES * sizeof(int), stream);
    k_deg_accum<<<(E4 + 255) / 256, 256, 0, stream>>>((const int4*)dst, deg);
    k_scan_part<<<SCAN_BLOCKS, 256, 0, stream>>>(deg, bsum);
    k_scan_top<<<1, 512, 0, stream>>>(bsum, boff);
    k_scan_write<<<SCAN_BLOCKS, 256, 0, stream>>>(deg, boff, row_start, cursor, dinv);
    k_scatter<<<(E4 + 255) / 256, 256, 0, stream>>>((const int4*)src, (const int4*)dst,
                                                    cursor, csr);

    // ----- layer 1: xs = bf16(dinv*x); aggregate -> GEMM (writes hs = bf16(relu*dinv)) -----
    k_xscale<<<(N_NODES * 16 + 255) / 256, 256, 0, stream>>>(x, dinv, xs);
    k_agg1<<<N_NODES / 8, 256, 0, stream>>>(row_start, csr, (const uint32*)xs, dinv, bufA);
    k_gemm8<IN_DIM, 1><<<N_NODES / 8, 256, 0, stream>>>(bufA, W1, b1, dinv, hs);

    // ----- layer 2: aggregate(hs) -> GEMM (f32 out) -----
    k_agg2<<<N_NODES / 8, 256, 0, stream>>>(row_start, csr, (const uint2*)hs, dinv, bufA);
    k_gemm8<HID, 0><<<N_NODES / 8, 256, 0, stream>>>(bufA, W2, b2, dinv, bufB);

    // ----- pool + head -----
    hipMemsetAsync(pooled, 0, (N_GRAPHS * HID + N_GRAPHS) * sizeof(float), stream);
    k_pool<<<(N_NODES + POOL_CHUNK - 1) / POOL_CHUNK, HID, 0, stream>>>(bufB, batch, pooled, cnt);
    k_head<<<1, 64, 0, stream>>>(pooled, cnt, Wfc, bfc, out);
}

// Round 7
// 368.600 us; speedup vs baseline: 1.3789x; 1.3789x over previous
//
#include <hip/hip_runtime.h>
#include <math.h>

#define N_NODES 100000
#define N_EDGES 1600000
#define IN_DIM 64
#define HID 128
#define OUT_DIM 2
#define N_GRAPHS 64

#define NBUK ((N_NODES + 255) / 256)         // 391 buckets of 256 nodes
#define BCAP 4608                            // slots per bucket (mean 4096, 8 sigma)
#define EPB 4096                             // edges per pass-1 block
#define NBLK_P1 ((N_EDGES + EPB - 1) / EPB)  // 391

typedef unsigned int uint32;

static __device__ __forceinline__ ushort f2bf(float f) {
    uint32 u = __float_as_uint(f);
    uint32 r = (u + 0x7fff + ((u >> 16) & 1)) >> 16;  // RNE
    return (ushort)r;
}
static __device__ __forceinline__ float bf2f(uint32 u) {
    return __uint_as_float(u << 16);
}
static __device__ __forceinline__ float bflo(uint32 u) { return bf2f(u & 0xffffu); }
static __device__ __forceinline__ float bfhi(uint32 u) { return bf2f(u >> 16); }

// ---------------- bucketed CSR build ----------------
__global__ __launch_bounds__(256) void k_gcur_init(int* __restrict__ gcur) {
    int i = blockIdx.x * 256 + threadIdx.x;
    if (i < NBUK) gcur[i] = i * BCAP;
}

// pass 1: partition edges into dst-buckets; one global atomic per (block,bucket)
__global__ __launch_bounds__(256) void k_pass1(const int* __restrict__ src,
                                               const int* __restrict__ dst,
                                               int* __restrict__ gcur,
                                               int* __restrict__ bsrc,
                                               int* __restrict__ bdst) {
    __shared__ int hist[NBUK];
    __shared__ int base[NBUK];
    int tid = threadIdx.x;
    for (int i = tid; i < NBUK; i += 256) hist[i] = 0;
    __syncthreads();
    int e0 = blockIdx.x * EPB;
#pragma unroll
    for (int k = 0; k < EPB / 256; ++k) {
        int e = e0 + k * 256 + tid;
        if (e < N_EDGES) atomicAdd(&hist[dst[e] >> 8], 1);
    }
    __syncthreads();
    for (int i = tid; i < NBUK; i += 256) {
        int c = hist[i];
        base[i] = c ? atomicAdd(&gcur[i], c) : 0;
        hist[i] = 0;
    }
    __syncthreads();
#pragma unroll
    for (int k = 0; k < EPB / 256; ++k) {
        int e = e0 + k * 256 + tid;
        if (e < N_EDGES) {
            int d = dst[e];
            int s = src[e];
            int b = d >> 8;
            int r = atomicAdd(&hist[b], 1);
            int slot = base[b] + r;
            bsrc[slot] = s;
            bdst[slot] = d;
        }
    }
}

// exclusive scan of bucket sizes
__global__ __launch_bounds__(512) void k_bscan(const int* __restrict__ gcur,
                                               int* __restrict__ bstart,
                                               int* __restrict__ row_start) {
    __shared__ int s[512];
    int t = threadIdx.x;
    int v = (t < NBUK) ? (gcur[t] - t * BCAP) : 0;
    s[t] = v;
    __syncthreads();
    for (int off = 1; off < 512; off <<= 1) {
        int u = (t >= off) ? s[t - off] : 0;
        __syncthreads();
        s[t] += u;
        __syncthreads();
    }
    if (t < NBUK) bstart[t] = s[t] - v;
    if (t == 0) row_start[N_NODES] = N_EDGES;
}

// pass 2: per-bucket counting sort -> row_start, dinv, csr. No global atomics.
__global__ __launch_bounds__(256) void k_pass2(const int* __restrict__ gcur,
                                               const int* __restrict__ bstart,
                                               const int* __restrict__ bsrc,
                                               const int* __restrict__ bdst,
                                               int* __restrict__ row_start,
                                               float* __restrict__ dinv,
                                               int* __restrict__ csr) {
    __shared__ int cnt[256];
    __shared__ int sc[256];
    __shared__ int lst[256];
    int b = blockIdx.x;
    int tid = threadIdx.x;
    int node0 = b * 256;
    int nloc = N_NODES - node0;
    if (nloc > 256) nloc = 256;
    int bbase = b * BCAP;
    int Eb = gcur[b] - bbase;

    cnt[tid] = 0;
    __syncthreads();
    for (int i = tid; i < Eb; i += 256) atomicAdd(&cnt[bdst[bbase + i] & 255], 1);
    __syncthreads();
    int v = cnt[tid];
    sc[tid] = v;
    __syncthreads();
    for (int off = 1; off < 256; off <<= 1) {
        int u = (tid >= off) ? sc[tid - off] : 0;
        __syncthreads();
        sc[tid] += u;
        __syncthreads();
    }
    int excl = sc[tid] - v;
    lst[tid] = excl;
    int gb = bstart[b];
    if (tid < nloc) {
        row_start[node0 + tid] = gb + excl;
        dinv[node0 + tid] = rsqrtf((float)(v + 1));  // +1 self loop
    }
    cnt[tid] = 0;
    __syncthreads();
    for (int i = tid; i < Eb; i += 256) {
        int d = bdst[bbase + i];
        int s = bsrc[bbase + i];
        int dl = d & 255;
        int r = atomicAdd(&cnt[dl], 1);
        csr[gb + lst[dl] + r] = s;
    }
}

// ---------------- pre-scale x by dinv -> bf16 ----------------
__global__ __launch_bounds__(256) void k_xscale(const float* __restrict__ x,
                                                const float* __restrict__ dinv,
                                                ushort* __restrict__ xs) {
    int idx = blockIdx.x * 256 + threadIdx.x;
    if (idx >= N_NODES * 16) return;
    float d = dinv[idx >> 4];
    float4 v = ((const float4*)x)[idx];
    ushort4 o;
    o.x = f2bf(v.x * d);
    o.y = f2bf(v.y * d);
    o.z = f2bf(v.z * d);
    o.w = f2bf(v.w * d);
    ((ushort4*)xs)[idx] = o;
}

// ---------------- aggregation (gather, CSR, bf16 rows, MLP-unrolled) ----------------
__global__ __launch_bounds__(256) void k_agg1(const int* __restrict__ row_start,
                                              const int* __restrict__ csr,
                                              const uint32* __restrict__ xs,
                                              const float* __restrict__ dinv,
                                              float* __restrict__ out) {
    int d = blockIdx.x * 8 + (threadIdx.x >> 5);
    int l = threadIdx.x & 31;
    float dd = dinv[d];
    uint32 u = xs[(long long)d * 32 + l];
    float a0 = bflo(u), a1 = bfhi(u);
    int e = row_start[d];
    int eend = row_start[d + 1];
    for (; e + 3 < eend; e += 4) {
        int s0 = csr[e], s1 = csr[e + 1], s2 = csr[e + 2], s3 = csr[e + 3];
        uint32 w0 = xs[(long long)s0 * 32 + l];
        uint32 w1 = xs[(long long)s1 * 32 + l];
        uint32 w2 = xs[(long long)s2 * 32 + l];
        uint32 w3 = xs[(long long)s3 * 32 + l];
        a0 += bflo(w0) + bflo(w1) + bflo(w2) + bflo(w3);
        a1 += bfhi(w0) + bfhi(w1) + bfhi(w2) + bfhi(w3);
    }
    for (; e < eend; ++e) {
        uint32 w = xs[(long long)csr[e] * 32 + l];
        a0 += bflo(w);
        a1 += bfhi(w);
    }
    float2 o;
    o.x = a0 * dd;
    o.y = a1 * dd;
    ((float2*)out)[(long long)d * 32 + l] = o;
}

__global__ __launch_bounds__(256) void k_agg2(const int* __restrict__ row_start,
                                              const int* __restrict__ csr,
                                              const uint2* __restrict__ hs,
                                              const float* __restrict__ dinv,
                                              float* __restrict__ out) {
    int d = blockIdx.x * 8 + (threadIdx.x >> 5);
    int l = threadIdx.x & 31;
    float dd = dinv[d];
    uint2 u = hs[(long long)d * 32 + l];
    float a0 = bflo(u.x), a1 = bfhi(u.x), a2 = bflo(u.y), a3 = bfhi(u.y);
    int e = row_start[d];
    int eend = row_start[d + 1];
    for (; e + 3 < eend; e += 4) {
        int s0 = csr[e], s1 = csr[e + 1], s2 = csr[e + 2], s3 = csr[e + 3];
        uint2 w0 = hs[(long long)s0 * 32 + l];
        uint2 w1 = hs[(long long)s1 * 32 + l];
        uint2 w2 = hs[(long long)s2 * 32 + l];
        uint2 w3 = hs[(long long)s3 * 32 + l];
        a0 += bflo(w0.x) + bflo(w1.x) + bflo(w2.x) + bflo(w3.x);
        a1 += bfhi(w0.x) + bfhi(w1.x) + bfhi(w2.x) + bfhi(w3.x);
        a2 += bflo(w0.y) + bflo(w1.y) + bflo(w2.y) + bflo(w3.y);
        a3 += bfhi(w0.y) + bfhi(w1.y) + bfhi(w2.y) + bfhi(w3.y);
    }
    for (; e < eend; ++e) {
        uint2 w = hs[(long long)csr[e] * 32 + l];
        a0 += bflo(w.x);
        a1 += bfhi(w.x);
        a2 += bflo(w.y);
        a3 += bfhi(w.y);
    }
    float4 o;
    o.x = a0 * dd;
    o.y = a1 * dd;
    o.z = a2 * dd;
    o.w = a3 * dd;
    ((float4*)out)[(long long)d * 32 + l] = o;
}

// ---------------- fused GEMM: out[N,HID] = relu(in[N,K] @ W + b) ----------------
template <int K, int OUT_BF>
__global__ __launch_bounds__(256) void k_gemm8(const float* __restrict__ in,
                                               const float* __restrict__ W,
                                               const float* __restrict__ bias,
                                               const float* __restrict__ dinv,
                                               void* __restrict__ outv) {
    __shared__ float xT[K * 8];
    int row0 = blockIdx.x * 8;
    int tid = threadIdx.x;
    for (int i = tid; i < 8 * K; i += 256) {
        int r = i / K, k = i % K;
        xT[k * 8 + r] = in[(long long)(row0 + r) * K + k];
    }
    __syncthreads();
    int j = tid & 127;
    int rh = tid >> 7;
    float a0 = 0.f, a1 = 0.f, a2 = 0.f, a3 = 0.f;
#pragma unroll 8
    for (int k = 0; k < K; ++k) {
        float w = W[k * HID + j];
        float4 xv = *(const float4*)&xT[k * 8 + rh * 4];
        a0 += w * xv.x;
        a1 += w * xv.y;
        a2 += w * xv.z;
        a3 += w * xv.w;
    }
    float b = bias[j];
    float acc[4] = {a0, a1, a2, a3};
#pragma unroll
    for (int r = 0; r < 4; ++r) {
        int row = row0 + rh * 4 + r;
        float v = acc[r] + b;
        v = v > 0.f ? v : 0.f;
        if (OUT_BF) {
            ((ushort*)outv)[(long long)row * HID + j] = f2bf(v * dinv[row]);
        } else {
            ((float*)outv)[(long long)row * HID + j] = v;
        }
    }
}

// ---------------- pooling ----------------
#define POOL_CHUNK 256
__global__ void k_pool(const float* __restrict__ h, const int* __restrict__ batch,
                       float* __restrict__ pooled, float* __restrict__ cnt) {
    int n0 = blockIdx.x * POOL_CHUNK;
    int n1 = n0 + POOL_CHUNK;
    if (n1 > N_NODES) n1 = N_NODES;
    if (n0 >= N_NODES) return;
    int j = threadIdx.x;  // 0..127
    float acc = 0.f;
    int cur = batch[n0];
    int c_local = 0;
    for (int n = n0; n < n1; ++n) {
        int g = batch[n];
        if (g != cur) {
            atomicAdd(&pooled[cur * HID + j], acc);
            if (j == 0) atomicAdd(&cnt[cur], (float)c_local);
            acc = 0.f;
            c_local = 0;
            cur = g;
        }
        acc += h[(long long)n * HID + j];
        ++c_local;
    }
    atomicAdd(&pooled[cur * HID + j], acc);
    if (j == 0) atomicAdd(&cnt[cur], (float)c_local);
}

// ---------------- head ----------------
__global__ void k_head(const float* __restrict__ pooled, const float* __restrict__ cnt,
                       const float* __restrict__ Wfc, const float* __restrict__ bfc,
                       float* __restrict__ out) {
    int g = threadIdx.x;
    if (g >= N_GRAPHS) return;
    float inv = 1.0f / fmaxf(cnt[g], 1.0f);
    float l0 = bfc[0], l1 = bfc[1];
    for (int j = 0; j < HID; ++j) {
        float p = pooled[g * HID + j] * inv;
        l0 += p * Wfc[j * OUT_DIM + 0];
        l1 += p * Wfc[j * OUT_DIM + 1];
    }
    float m = fmaxf(l0, l1);
    float lse = m + logf(expf(l0 - m) + expf(l1 - m));
    out[g * OUT_DIM + 0] = l0 - lse;
    out[g * OUT_DIM + 1] = l1 - lse;
}

extern "C" void kernel_launch(void* const* d_in, const int* in_sizes, int n_in,
                              void* d_out, int out_size, void* d_ws, size_t ws_size,
                              hipStream_t stream) {
    const float* x   = (const float*)d_in[0];
    const float* W1  = (const float*)d_in[1];
    const float* b1  = (const float*)d_in[2];
    const float* W2  = (const float*)d_in[3];
    const float* b2  = (const float*)d_in[4];
    const float* Wfc = (const float*)d_in[5];
    const float* bfc = (const float*)d_in[6];
    const int* ei    = (const int*)d_in[7];   // [2, E]
    const int* batch = (const int*)d_in[8];
    const int* src = ei;
    const int* dst = ei + N_EDGES;
    float* out = (float*)d_out;

    // workspace layout
    float* bufA = (float*)d_ws;                    // N*HID f32 (agg outputs)
    float* bufB = bufA + (long long)N_NODES * HID; // N*HID f32 (xs/hs bf16, gemm2 out)
    // bucket arrays overlay bufA (dead before k_agg1 writes it)
    int* bsrc = (int*)bufA;                        // NBUK*BCAP
    int* bdst = bsrc + NBUK * BCAP;                // NBUK*BCAP  (14.4 MB total < 51 MB)
    ushort* xs = (ushort*)bufB;                    // N*64 bf16
    ushort* hs = (ushort*)bufB;                    // N*128 bf16
    int* row_start = (int*)(bufB + (long long)N_NODES * HID);  // N+1
    float* dinv = (float*)(row_start + N_NODES + 1);  // N
    int* gcur = (int*)(dinv + N_NODES);            // NBUK
    int* bstart = gcur + NBUK;                     // NBUK
    int* csr = bstart + NBUK;                      // E
    float* pooled = (float*)(csr + N_EDGES);       // G*HID
    float* cnt = pooled + N_GRAPHS * HID;          // G

    // ----- CSR build (bucketed, no per-edge global atomics) -----
    k_gcur_init<<<(NBUK + 255) / 256, 256, 0, stream>>>(gcur);
    k_pass1<<<NBLK_P1, 256, 0, stream>>>(src, dst, gcur, bsrc, bdst);
    k_bscan<<<1, 512, 0, stream>>>(gcur, bstart, row_start);
    k_pass2<<<NBUK, 256, 0, stream>>>(gcur, bstart, bsrc, bdst, row_start, dinv, csr);

    // ----- layer 1: xs = bf16(dinv*x); aggregate -> GEMM (writes hs = bf16(relu*dinv)) -----
    k_xscale<<<(N_NODES * 16 + 255) / 256, 256, 0, stream>>>(x, dinv, xs);
    k_agg1<<<N_NODES / 8, 256, 0, stream>>>(row_start, csr, (const uint32*)xs, dinv, bufA);
    k_gemm8<IN_DIM, 1><<<N_NODES / 8, 256, 0, stream>>>(bufA, W1, b1, dinv, hs);

    // ----- layer 2: aggregate(hs) -> GEMM (f32 out) -----
    k_agg2<<<N_NODES / 8, 256, 0, stream>>>(row_start, csr, (const uint2*)hs, dinv, bufA);
    k_gemm8<HID, 0><<<N_NODES / 8, 256, 0, stream>>>(bufA, W2, b2, dinv, bufB);

    // ----- pool + head -----
    hipMemsetAsync(pooled, 0, (N_GRAPHS * HID + N_GRAPHS) * sizeof(float), stream);
    k_pool<<<(N_NODES + POOL_CHUNK - 1) / POOL_CHUNK, HID, 0, stream>>>(bufB, batch, pooled, cnt);
    k_head<<<1, 64, 0, stream>>>(pooled, cnt, Wfc, bfc, out);
}

// Round 8
// 309.290 us; speedup vs baseline: 1.6433x; 1.1918x over previous
//
#include <hip/hip_runtime.h>
#include <math.h>

#define N_NODES 100000
#define N_EDGES 1600000
#define IN_DIM 64
#define HID 128
#define OUT_DIM 2
#define N_GRAPHS 64

#define NBUK ((N_NODES + 255) / 256)         // 391 buckets of 256 nodes
#define BCAP 4608                            // slots per bucket (mean 4096, 8 sigma)
#define EPB 4096                             // edges per pass-1 block
#define NBLK_P1 ((N_EDGES + EPB - 1) / EPB)  // 391

#define PCHUNK 256                           // pool rows per block
#define MAXCH 8                              // max chunks per graph (mean 1562 rows, 12 sigma < 2048)

typedef unsigned int uint32;

static __device__ __forceinline__ ushort f2bf(float f) {
    uint32 u = __float_as_uint(f);
    uint32 r = (u + 0x7fff + ((u >> 16) & 1)) >> 16;  // RNE
    return (ushort)r;
}
static __device__ __forceinline__ float bf2f(uint32 u) {
    return __uint_as_float(u << 16);
}
static __device__ __forceinline__ float bflo(uint32 u) { return bf2f(u & 0xffffu); }
static __device__ __forceinline__ float bfhi(uint32 u) { return bf2f(u >> 16); }

// ---------------- bucketed CSR build ----------------
__global__ __launch_bounds__(256) void k_gcur_init(int* __restrict__ gcur) {
    int i = blockIdx.x * 256 + threadIdx.x;
    if (i < NBUK) gcur[i] = i * BCAP;
}

__global__ __launch_bounds__(256) void k_pass1(const int* __restrict__ src,
                                               const int* __restrict__ dst,
                                               int* __restrict__ gcur,
                                               int* __restrict__ bsrc,
                                               int* __restrict__ bdst) {
    __shared__ int hist[NBUK];
    __shared__ int base[NBUK];
    int tid = threadIdx.x;
    for (int i = tid; i < NBUK; i += 256) hist[i] = 0;
    __syncthreads();
    int e0 = blockIdx.x * EPB;
#pragma unroll
    for (int k = 0; k < EPB / 256; ++k) {
        int e = e0 + k * 256 + tid;
        if (e < N_EDGES) atomicAdd(&hist[dst[e] >> 8], 1);
    }
    __syncthreads();
    for (int i = tid; i < NBUK; i += 256) {
        int c = hist[i];
        base[i] = c ? atomicAdd(&gcur[i], c) : 0;
        hist[i] = 0;
    }
    __syncthreads();
#pragma unroll
    for (int k = 0; k < EPB / 256; ++k) {
        int e = e0 + k * 256 + tid;
        if (e < N_EDGES) {
            int d = dst[e];
            int s = src[e];
            int b = d >> 8;
            int r = atomicAdd(&hist[b], 1);
            int slot = base[b] + r;
            bsrc[slot] = s;
            bdst[slot] = d;
        }
    }
}

__global__ __launch_bounds__(512) void k_bscan(const int* __restrict__ gcur,
                                               int* __restrict__ bstart,
                                               int* __restrict__ row_start) {
    __shared__ int s[512];
    int t = threadIdx.x;
    int v = (t < NBUK) ? (gcur[t] - t * BCAP) : 0;
    s[t] = v;
    __syncthreads();
    for (int off = 1; off < 512; off <<= 1) {
        int u = (t >= off) ? s[t - off] : 0;
        __syncthreads();
        s[t] += u;
        __syncthreads();
    }
    if (t < NBUK) bstart[t] = s[t] - v;
    if (t == 0) row_start[N_NODES] = N_EDGES;
}

__global__ __launch_bounds__(256) void k_pass2(const int* __restrict__ gcur,
                                               const int* __restrict__ bstart,
                                               const int* __restrict__ bsrc,
                                               const int* __restrict__ bdst,
                                               int* __restrict__ row_start,
                                               float* __restrict__ dinv,
                                               int* __restrict__ csr) {
    __shared__ int cnt[256];
    __shared__ int sc[256];
    __shared__ int lst[256];
    int b = blockIdx.x;
    int tid = threadIdx.x;
    int node0 = b * 256;
    int nloc = N_NODES - node0;
    if (nloc > 256) nloc = 256;
    int bbase = b * BCAP;
    int Eb = gcur[b] - bbase;

    cnt[tid] = 0;
    __syncthreads();
    for (int i = tid; i < Eb; i += 256) atomicAdd(&cnt[bdst[bbase + i] & 255], 1);
    __syncthreads();
    int v = cnt[tid];
    sc[tid] = v;
    __syncthreads();
    for (int off = 1; off < 256; off <<= 1) {
        int u = (tid >= off) ? sc[tid - off] : 0;
        __syncthreads();
        sc[tid] += u;
        __syncthreads();
    }
    int excl = sc[tid] - v;
    lst[tid] = excl;
    int gb = bstart[b];
    if (tid < nloc) {
        row_start[node0 + tid] = gb + excl;
        dinv[node0 + tid] = rsqrtf((float)(v + 1));  // +1 self loop
    }
    cnt[tid] = 0;
    __syncthreads();
    for (int i = tid; i < Eb; i += 256) {
        int d = bdst[bbase + i];
        int s = bsrc[bbase + i];
        int dl = d & 255;
        int r = atomicAdd(&cnt[dl], 1);
        csr[gb + lst[dl] + r] = s;
    }
}

// ---------------- graph boundaries from sorted batch ----------------
__global__ __launch_bounds__(256) void k_gbound(const int* __restrict__ batch,
                                                int* __restrict__ gstart) {
    int n = blockIdx.x * 256 + threadIdx.x;
    if (n >= N_NODES) return;
    if (n == 0) {
        for (int g = 0; g <= batch[0]; ++g) gstart[g] = 0;
    } else {
        int a = batch[n - 1], b = batch[n];
        for (int g = a + 1; g <= b; ++g) gstart[g] = n;
    }
    if (n == N_NODES - 1) {
        for (int g = batch[n] + 1; g <= N_GRAPHS; ++g) gstart[g] = N_NODES;
    }
}

// ---------------- pre-scale x by dinv -> bf16 ----------------
__global__ __launch_bounds__(256) void k_xscale(const float* __restrict__ x,
                                                const float* __restrict__ dinv,
                                                ushort* __restrict__ xs) {
    int idx = blockIdx.x * 256 + threadIdx.x;
    if (idx >= N_NODES * 16) return;
    float d = dinv[idx >> 4];
    float4 v = ((const float4*)x)[idx];
    ushort4 o;
    o.x = f2bf(v.x * d);
    o.y = f2bf(v.y * d);
    o.z = f2bf(v.z * d);
    o.w = f2bf(v.w * d);
    ((ushort4*)xs)[idx] = o;
}

// ---------------- aggregation (gather, CSR, bf16 rows, MLP-unrolled) ----------------
__global__ __launch_bounds__(256) void k_agg1(const int* __restrict__ row_start,
                                              const int* __restrict__ csr,
                                              const uint32* __restrict__ xs,
                                              const float* __restrict__ dinv,
                                              float* __restrict__ out) {
    int d = blockIdx.x * 8 + (threadIdx.x >> 5);
    int l = threadIdx.x & 31;
    float dd = dinv[d];
    uint32 u = xs[(long long)d * 32 + l];
    float a0 = bflo(u), a1 = bfhi(u);
    int e = row_start[d];
    int eend = row_start[d + 1];
    for (; e + 3 < eend; e += 4) {
        int s0 = csr[e], s1 = csr[e + 1], s2 = csr[e + 2], s3 = csr[e + 3];
        uint32 w0 = xs[(long long)s0 * 32 + l];
        uint32 w1 = xs[(long long)s1 * 32 + l];
        uint32 w2 = xs[(long long)s2 * 32 + l];
        uint32 w3 = xs[(long long)s3 * 32 + l];
        a0 += bflo(w0) + bflo(w1) + bflo(w2) + bflo(w3);
        a1 += bfhi(w0) + bfhi(w1) + bfhi(w2) + bfhi(w3);
    }
    for (; e < eend; ++e) {
        uint32 w = xs[(long long)csr[e] * 32 + l];
        a0 += bflo(w);
        a1 += bfhi(w);
    }
    float2 o;
    o.x = a0 * dd;
    o.y = a1 * dd;
    ((float2*)out)[(long long)d * 32 + l] = o;
}

__global__ __launch_bounds__(256) void k_agg2(const int* __restrict__ row_start,
                                              const int* __restrict__ csr,
                                              const uint2* __restrict__ hs,
                                              const float* __restrict__ dinv,
                                              float* __restrict__ out) {
    int d = blockIdx.x * 8 + (threadIdx.x >> 5);
    int l = threadIdx.x & 31;
    float dd = dinv[d];
    uint2 u = hs[(long long)d * 32 + l];
    float a0 = bflo(u.x), a1 = bfhi(u.x), a2 = bflo(u.y), a3 = bfhi(u.y);
    int e = row_start[d];
    int eend = row_start[d + 1];
    for (; e + 3 < eend; e += 4) {
        int s0 = csr[e], s1 = csr[e + 1], s2 = csr[e + 2], s3 = csr[e + 3];
        uint2 w0 = hs[(long long)s0 * 32 + l];
        uint2 w1 = hs[(long long)s1 * 32 + l];
        uint2 w2 = hs[(long long)s2 * 32 + l];
        uint2 w3 = hs[(long long)s3 * 32 + l];
        a0 += bflo(w0.x) + bflo(w1.x) + bflo(w2.x) + bflo(w3.x);
        a1 += bfhi(w0.x) + bfhi(w1.x) + bfhi(w2.x) + bfhi(w3.x);
        a2 += bflo(w0.y) + bflo(w1.y) + bflo(w2.y) + bflo(w3.y);
        a3 += bfhi(w0.y) + bfhi(w1.y) + bfhi(w2.y) + bfhi(w3.y);
    }
    for (; e < eend; ++e) {
        uint2 w = hs[(long long)csr[e] * 32 + l];
        a0 += bflo(w.x);
        a1 += bfhi(w.x);
        a2 += bflo(w.y);
        a3 += bfhi(w.y);
    }
    float4 o;
    o.x = a0 * dd;
    o.y = a1 * dd;
    o.z = a2 * dd;
    o.w = a3 * dd;
    ((float4*)out)[(long long)d * 32 + l] = o;
}

// ---------------- fused GEMM: out[N,HID] = relu(in[N,K] @ W + b) ----------------
template <int K, int OUT_BF>
__global__ __launch_bounds__(256) void k_gemm8(const float* __restrict__ in,
                                               const float* __restrict__ W,
                                               const float* __restrict__ bias,
                                               const float* __restrict__ dinv,
                                               void* __restrict__ outv) {
    __shared__ float xT[K * 8];
    int row0 = blockIdx.x * 8;
    int tid = threadIdx.x;
    for (int i = tid; i < 8 * K; i += 256) {
        int r = i / K, k = i % K;
        xT[k * 8 + r] = in[(long long)(row0 + r) * K + k];
    }
    __syncthreads();
    int j = tid & 127;
    int rh = tid >> 7;
    float a0 = 0.f, a1 = 0.f, a2 = 0.f, a3 = 0.f;
#pragma unroll 8
    for (int k = 0; k < K; ++k) {
        float w = W[k * HID + j];
        float4 xv = *(const float4*)&xT[k * 8 + rh * 4];
        a0 += w * xv.x;
        a1 += w * xv.y;
        a2 += w * xv.z;
        a3 += w * xv.w;
    }
    float b = bias[j];
    float acc[4] = {a0, a1, a2, a3};
#pragma unroll
    for (int r = 0; r < 4; ++r) {
        int row = row0 + rh * 4 + r;
        float v = acc[r] + b;
        v = v > 0.f ? v : 0.f;
        if (OUT_BF) {
            ((ushort*)outv)[(long long)row * HID + j] = f2bf(v * dinv[row]);
        } else {
            ((float*)outv)[(long long)row * HID + j] = v;
        }
    }
}

// ---------------- pooling: one block per (graph, chunk) ----------------
__global__ __launch_bounds__(256) void k_pool(const float* __restrict__ h,
                                              const int* __restrict__ gstart,
                                              float* __restrict__ pooled) {
    int g = blockIdx.x >> 3;   // / MAXCH
    int c = blockIdx.x & (MAXCH - 1);
    int r0 = gstart[g] + c * PCHUNK;
    int r1 = gstart[g + 1];
    if (r0 >= r1) return;
    int rend = r0 + PCHUNK;
    if (rend > r1) rend = r1;
    int j = threadIdx.x & 127;
    int half = threadIdx.x >> 7;
    float a0 = 0.f, a1 = 0.f, a2 = 0.f, a3 = 0.f;
    int r = r0 + half;
    for (; r + 6 < rend; r += 8) {
        a0 += h[(long long)r * HID + j];
        a1 += h[(long long)(r + 2) * HID + j];
        a2 += h[(long long)(r + 4) * HID + j];
        a3 += h[(long long)(r + 6) * HID + j];
    }
    for (; r < rend; r += 2) a0 += h[(long long)r * HID + j];
    __shared__ float red[256];
    red[threadIdx.x] = (a0 + a1) + (a2 + a3);
    __syncthreads();
    if (half == 0) atomicAdd(&pooled[g * HID + j], red[j] + red[j + 128]);
}

// ---------------- head ----------------
__global__ void k_head(const float* __restrict__ pooled, const int* __restrict__ gstart,
                       const float* __restrict__ Wfc, const float* __restrict__ bfc,
                       float* __restrict__ out) {
    int g = threadIdx.x;
    if (g >= N_GRAPHS) return;
    float inv = 1.0f / fmaxf((float)(gstart[g + 1] - gstart[g]), 1.0f);
    float l0 = bfc[0], l1 = bfc[1];
    for (int j = 0; j < HID; ++j) {
        float p = pooled[g * HID + j] * inv;
        l0 += p * Wfc[j * OUT_DIM + 0];
        l1 += p * Wfc[j * OUT_DIM + 1];
    }
    float m = fmaxf(l0, l1);
    float lse = m + logf(expf(l0 - m) + expf(l1 - m));
    out[g * OUT_DIM + 0] = l0 - lse;
    out[g * OUT_DIM + 1] = l1 - lse;
}

extern "C" void kernel_launch(void* const* d_in, const int* in_sizes, int n_in,
                              void* d_out, int out_size, void* d_ws, size_t ws_size,
                              hipStream_t stream) {
    const float* x   = (const float*)d_in[0];
    const float* W1  = (const float*)d_in[1];
    const float* b1  = (const float*)d_in[2];
    const float* W2  = (const float*)d_in[3];
    const float* b2  = (const float*)d_in[4];
    const float* Wfc = (const float*)d_in[5];
    const float* bfc = (const float*)d_in[6];
    const int* ei    = (const int*)d_in[7];   // [2, E]
    const int* batch = (const int*)d_in[8];
    const int* src = ei;
    const int* dst = ei + N_EDGES;
    float* out = (float*)d_out;

    // workspace layout
    float* bufA = (float*)d_ws;                    // N*HID f32 (agg outputs)
    float* bufB = bufA + (long long)N_NODES * HID; // N*HID f32 (xs/hs bf16, gemm2 out)
    int* bsrc = (int*)bufA;                        // NBUK*BCAP (overlay, dead before agg1)
    int* bdst = bsrc + NBUK * BCAP;                // NBUK*BCAP
    ushort* xs = (ushort*)bufB;                    // N*64 bf16
    ushort* hs = (ushort*)bufB;                    // N*128 bf16
    int* row_start = (int*)(bufB + (long long)N_NODES * HID);  // N+1
    float* dinv = (float*)(row_start + N_NODES + 1);  // N
    int* gcur = (int*)(dinv + N_NODES);            // NBUK
    int* bstart = gcur + NBUK;                     // NBUK
    int* gstart = bstart + NBUK;                   // N_GRAPHS+1
    int* csr = gstart + (N_GRAPHS + 1);            // E
    float* pooled = (float*)(csr + N_EDGES);       // G*HID

    // ----- CSR build (bucketed, no per-edge global atomics) -----
    k_gcur_init<<<(NBUK + 255) / 256, 256, 0, stream>>>(gcur);
    k_pass1<<<NBLK_P1, 256, 0, stream>>>(src, dst, gcur, bsrc, bdst);
    k_bscan<<<1, 512, 0, stream>>>(gcur, bstart, row_start);
    k_pass2<<<NBUK, 256, 0, stream>>>(gcur, bstart, bsrc, bdst, row_start, dinv, csr);
    k_gbound<<<(N_NODES + 255) / 256, 256, 0, stream>>>(batch, gstart);

    // ----- layer 1 -----
    k_xscale<<<(N_NODES * 16 + 255) / 256, 256, 0, stream>>>(x, dinv, xs);
    k_agg1<<<N_NODES / 8, 256, 0, stream>>>(row_start, csr, (const uint32*)xs, dinv, bufA);
    k_gemm8<IN_DIM, 1><<<N_NODES / 8, 256, 0, stream>>>(bufA, W1, b1, dinv, hs);

    // ----- layer 2 -----
    k_agg2<<<N_NODES / 8, 256, 0, stream>>>(row_start, csr, (const uint2*)hs, dinv, bufA);
    k_gemm8<HID, 0><<<N_NODES / 8, 256, 0, stream>>>(bufA, W2, b2, dinv, bufB);

    // ----- pool + head -----
    hipMemsetAsync(pooled, 0, N_GRAPHS * HID * sizeof(float), stream);
    k_pool<<<N_GRAPHS * MAXCH, 256, 0, stream>>>(bufB, gstart, pooled);
    k_head<<<1, 64, 0, stream>>>(pooled, gstart, Wfc, bfc, out);
}

// Round 9
// 242.170 us; speedup vs baseline: 2.0988x; 1.2772x over previous
//
#include <hip/hip_runtime.h>
#include <math.h>

#define N_NODES 100000
#define N_EDGES 1600000
#define IN_DIM 64
#define HID 128
#define OUT_DIM 2
#define N_GRAPHS 64

#define NBUK ((N_NODES + 255) / 256)         // 391 buckets of 256 nodes
#define BCAP 4608                            // slots per bucket (mean 4096, 8 sigma)
#define EPB 4096                             // edges per pass-1 block
#define NBLK_P1 ((N_EDGES + EPB - 1) / EPB)  // 391

#define PCHUNK 256                           // pool rows per block
#define MAXCH 8                              // max chunks per graph

typedef unsigned int uint32;
typedef __attribute__((ext_vector_type(8))) short bf16x8;
typedef __attribute__((ext_vector_type(4))) float f32x4;

static __device__ __forceinline__ ushort f2bf(float f) {
    uint32 u = __float_as_uint(f);
    uint32 r = (u + 0x7fff + ((u >> 16) & 1)) >> 16;  // RNE
    return (ushort)r;
}
static __device__ __forceinline__ float bf2f(uint32 u) {
    return __uint_as_float(u << 16);
}
static __device__ __forceinline__ float bflo(uint32 u) { return bf2f(u & 0xffffu); }
static __device__ __forceinline__ float bfhi(uint32 u) { return bf2f(u >> 16); }

// ---------------- bucketed CSR build ----------------
__global__ __launch_bounds__(256) void k_gcur_init(int* __restrict__ gcur) {
    int i = blockIdx.x * 256 + threadIdx.x;
    if (i < NBUK) gcur[i] = i * BCAP;
}

__global__ __launch_bounds__(256) void k_pass1(const int* __restrict__ src,
                                               const int* __restrict__ dst,
                                               int* __restrict__ gcur,
                                               int* __restrict__ bsrc,
                                               int* __restrict__ bdst) {
    __shared__ int hist[NBUK];
    __shared__ int base[NBUK];
    int tid = threadIdx.x;
    for (int i = tid; i < NBUK; i += 256) hist[i] = 0;
    __syncthreads();
    int e0 = blockIdx.x * EPB;
#pragma unroll
    for (int k = 0; k < EPB / 256; ++k) {
        int e = e0 + k * 256 + tid;
        if (e < N_EDGES) atomicAdd(&hist[dst[e] >> 8], 1);
    }
    __syncthreads();
    for (int i = tid; i < NBUK; i += 256) {
        int c = hist[i];
        base[i] = c ? atomicAdd(&gcur[i], c) : 0;
        hist[i] = 0;
    }
    __syncthreads();
#pragma unroll
    for (int k = 0; k < EPB / 256; ++k) {
        int e = e0 + k * 256 + tid;
        if (e < N_EDGES) {
            int d = dst[e];
            int s = src[e];
            int b = d >> 8;
            int r = atomicAdd(&hist[b], 1);
            int slot = base[b] + r;
            bsrc[slot] = s;
            bdst[slot] = d;
        }
    }
}

__global__ __launch_bounds__(512) void k_bscan(const int* __restrict__ gcur,
                                               int* __restrict__ bstart,
                                               int* __restrict__ row_start) {
    __shared__ int s[512];
    int t = threadIdx.x;
    int v = (t < NBUK) ? (gcur[t] - t * BCAP) : 0;
    s[t] = v;
    __syncthreads();
    for (int off = 1; off < 512; off <<= 1) {
        int u = (t >= off) ? s[t - off] : 0;
        __syncthreads();
        s[t] += u;
        __syncthreads();
    }
    if (t < NBUK) bstart[t] = s[t] - v;
    if (t == 0) row_start[N_NODES] = N_EDGES;
}

__global__ __launch_bounds__(256) void k_pass2(const int* __restrict__ gcur,
                                               const int* __restrict__ bstart,
                                               const int* __restrict__ bsrc,
                                               const int* __restrict__ bdst,
                                               int* __restrict__ row_start,
                                               float* __restrict__ dinv,
                                               int* __restrict__ csr) {
    __shared__ int cnt[256];
    __shared__ int sc[256];
    __shared__ int lst[256];
    int b = blockIdx.x;
    int tid = threadIdx.x;
    int node0 = b * 256;
    int nloc = N_NODES - node0;
    if (nloc > 256) nloc = 256;
    int bbase = b * BCAP;
    int Eb = gcur[b] - bbase;

    cnt[tid] = 0;
    __syncthreads();
    for (int i = tid; i < Eb; i += 256) atomicAdd(&cnt[bdst[bbase + i] & 255], 1);
    __syncthreads();
    int v = cnt[tid];
    sc[tid] = v;
    __syncthreads();
    for (int off = 1; off < 256; off <<= 1) {
        int u = (tid >= off) ? sc[tid - off] : 0;
        __syncthreads();
        sc[tid] += u;
        __syncthreads();
    }
    int excl = sc[tid] - v;
    lst[tid] = excl;
    int gb = bstart[b];
    if (tid < nloc) {
        row_start[node0 + tid] = gb + excl;
        dinv[node0 + tid] = rsqrtf((float)(v + 1));  // +1 self loop
    }
    cnt[tid] = 0;
    __syncthreads();
    for (int i = tid; i < Eb; i += 256) {
        int d = bdst[bbase + i];
        int s = bsrc[bbase + i];
        int dl = d & 255;
        int r = atomicAdd(&cnt[dl], 1);
        csr[gb + lst[dl] + r] = s;
    }
}

// ---------------- graph boundaries from sorted batch ----------------
__global__ __launch_bounds__(256) void k_gbound(const int* __restrict__ batch,
                                                int* __restrict__ gstart) {
    int n = blockIdx.x * 256 + threadIdx.x;
    if (n >= N_NODES) return;
    if (n == 0) {
        for (int g = 0; g <= batch[0]; ++g) gstart[g] = 0;
    } else {
        int a = batch[n - 1], b = batch[n];
        for (int g = a + 1; g <= b; ++g) gstart[g] = n;
    }
    if (n == N_NODES - 1) {
        for (int g = batch[n] + 1; g <= N_GRAPHS; ++g) gstart[g] = N_NODES;
    }
}

// ---------------- pre-scale x by dinv -> bf16 ----------------
__global__ __launch_bounds__(256) void k_xscale(const float* __restrict__ x,
                                                const float* __restrict__ dinv,
                                                ushort* __restrict__ xs) {
    int idx = blockIdx.x * 256 + threadIdx.x;
    if (idx >= N_NODES * 16) return;
    float d = dinv[idx >> 4];
    float4 v = ((const float4*)x)[idx];
    ushort4 o;
    o.x = f2bf(v.x * d);
    o.y = f2bf(v.y * d);
    o.z = f2bf(v.z * d);
    o.w = f2bf(v.w * d);
    ((ushort4*)xs)[idx] = o;
}

// ---------------- aggregation (gather, CSR, bf16 in AND out) ----------------
__global__ __launch_bounds__(256) void k_agg1(const int* __restrict__ row_start,
                                              const int* __restrict__ csr,
                                              const uint32* __restrict__ xs,
                                              const float* __restrict__ dinv,
                                              uint32* __restrict__ outb) {
    int d = blockIdx.x * 8 + (threadIdx.x >> 5);
    int l = threadIdx.x & 31;
    float dd = dinv[d];
    uint32 u = xs[(long long)d * 32 + l];
    float a0 = bflo(u), a1 = bfhi(u);
    int e = row_start[d];
    int eend = row_start[d + 1];
    for (; e + 3 < eend; e += 4) {
        int s0 = csr[e], s1 = csr[e + 1], s2 = csr[e + 2], s3 = csr[e + 3];
        uint32 w0 = xs[(long long)s0 * 32 + l];
        uint32 w1 = xs[(long long)s1 * 32 + l];
        uint32 w2 = xs[(long long)s2 * 32 + l];
        uint32 w3 = xs[(long long)s3 * 32 + l];
        a0 += bflo(w0) + bflo(w1) + bflo(w2) + bflo(w3);
        a1 += bfhi(w0) + bfhi(w1) + bfhi(w2) + bfhi(w3);
    }
    for (; e < eend; ++e) {
        uint32 w = xs[(long long)csr[e] * 32 + l];
        a0 += bflo(w);
        a1 += bfhi(w);
    }
    outb[(long long)d * 32 + l] = (uint32)f2bf(a0 * dd) | ((uint32)f2bf(a1 * dd) << 16);
}

__global__ __launch_bounds__(256) void k_agg2(const int* __restrict__ row_start,
                                              const int* __restrict__ csr,
                                              const uint2* __restrict__ hs,
                                              const float* __restrict__ dinv,
                                              uint2* __restrict__ outb) {
    int d = blockIdx.x * 8 + (threadIdx.x >> 5);
    int l = threadIdx.x & 31;
    float dd = dinv[d];
    uint2 u = hs[(long long)d * 32 + l];
    float a0 = bflo(u.x), a1 = bfhi(u.x), a2 = bflo(u.y), a3 = bfhi(u.y);
    int e = row_start[d];
    int eend = row_start[d + 1];
    for (; e + 3 < eend; e += 4) {
        int s0 = csr[e], s1 = csr[e + 1], s2 = csr[e + 2], s3 = csr[e + 3];
        uint2 w0 = hs[(long long)s0 * 32 + l];
        uint2 w1 = hs[(long long)s1 * 32 + l];
        uint2 w2 = hs[(long long)s2 * 32 + l];
        uint2 w3 = hs[(long long)s3 * 32 + l];
        a0 += bflo(w0.x) + bflo(w1.x) + bflo(w2.x) + bflo(w3.x);
        a1 += bfhi(w0.x) + bfhi(w1.x) + bfhi(w2.x) + bfhi(w3.x);
        a2 += bflo(w0.y) + bflo(w1.y) + bflo(w2.y) + bflo(w3.y);
        a3 += bfhi(w0.y) + bfhi(w1.y) + bfhi(w2.y) + bfhi(w3.y);
    }
    for (; e < eend; ++e) {
        uint2 w = hs[(long long)csr[e] * 32 + l];
        a0 += bflo(w.x);
        a1 += bfhi(w.x);
        a2 += bflo(w.y);
        a3 += bfhi(w.y);
    }
    uint2 o;
    o.x = (uint32)f2bf(a0 * dd) | ((uint32)f2bf(a1 * dd) << 16);
    o.y = (uint32)f2bf(a2 * dd) | ((uint32)f2bf(a3 * dd) << 16);
    outb[(long long)d * 32 + l] = o;
}

// ---------------- MFMA GEMM: out[N,128] = relu(A[N,K](bf16) @ W[K,128] + b) ----------------
// 4 waves/block, 64 rows x 128 cols per block. W -> bf16 transposed LDS tile.
template <int K, int OUT_BF>
__global__ __launch_bounds__(256) void k_gemm_mfma(const ushort* __restrict__ A,
                                                   const float* __restrict__ W,
                                                   const float* __restrict__ bias,
                                                   const float* __restrict__ dinv,
                                                   void* __restrict__ outv) {
    constexpr int KSTEPS = K / 32;
    constexpr int LDSK = K + 8;          // pad: col stride 4 banks -> 2-way (free)
    __shared__ ushort WT[128 * LDSK];    // [col][k] bf16
    int tid = threadIdx.x;
    for (int idx = tid; idx < K * 128; idx += 256) {
        int k = idx >> 7, c = idx & 127;
        WT[c * LDSK + k] = f2bf(W[idx]);
    }
    __syncthreads();

    int w = tid >> 6, l = tid & 63;
    int row0 = blockIdx.x * 64 + w * 16;
    int arow = row0 + (l & 15);
    if (arow > N_NODES - 1) arow = N_NODES - 1;
    int koff = (l >> 4) * 8;

    bf16x8 af[KSTEPS];
#pragma unroll
    for (int ks = 0; ks < KSTEPS; ++ks)
        af[ks] = *(const bf16x8*)(A + (long long)arow * K + ks * 32 + koff);

    f32x4 acc[8];
#pragma unroll
    for (int t = 0; t < 8; ++t) acc[t] = (f32x4){0.f, 0.f, 0.f, 0.f};

#pragma unroll
    for (int ks = 0; ks < KSTEPS; ++ks) {
#pragma unroll
        for (int t = 0; t < 8; ++t) {
            int c = t * 16 + (l & 15);
            bf16x8 bf = *(const bf16x8*)&WT[c * LDSK + ks * 32 + koff];
            acc[t] = __builtin_amdgcn_mfma_f32_16x16x32_bf16(af[ks], bf, acc[t], 0, 0, 0);
        }
    }

    int rbase = row0 + ((l >> 4) << 2);
#pragma unroll
    for (int t = 0; t < 8; ++t) {
        int col = t * 16 + (l & 15);
        float bb = bias[col];
#pragma unroll
        for (int i = 0; i < 4; ++i) {
            int row = rbase + i;
            if (row < N_NODES) {
                float v = acc[t][i] + bb;
                v = v > 0.f ? v : 0.f;
                if (OUT_BF) {
                    ((ushort*)outv)[(long long)row * HID + col] = f2bf(v * dinv[row]);
                } else {
                    ((float*)outv)[(long long)row * HID + col] = v;
                }
            }
        }
    }
}

// ---------------- pooling: one block per (graph, chunk) ----------------
__global__ __launch_bounds__(256) void k_pool(const float* __restrict__ h,
                                              const int* __restrict__ gstart,
                                              float* __restrict__ pooled) {
    int g = blockIdx.x >> 3;   // / MAXCH
    int c = blockIdx.x & (MAXCH - 1);
    int r0 = gstart[g] + c * PCHUNK;
    int r1 = gstart[g + 1];
    if (r0 >= r1) return;
    int rend = r0 + PCHUNK;
    if (rend > r1) rend = r1;
    int j = threadIdx.x & 127;
    int half = threadIdx.x >> 7;
    float a0 = 0.f, a1 = 0.f, a2 = 0.f, a3 = 0.f;
    int r = r0 + half;
    for (; r + 6 < rend; r += 8) {
        a0 += h[(long long)r * HID + j];
        a1 += h[(long long)(r + 2) * HID + j];
        a2 += h[(long long)(r + 4) * HID + j];
        a3 += h[(long long)(r + 6) * HID + j];
    }
    for (; r < rend; r += 2) a0 += h[(long long)r * HID + j];
    __shared__ float red[256];
    red[threadIdx.x] = (a0 + a1) + (a2 + a3);
    __syncthreads();
    if (half == 0) atomicAdd(&pooled[g * HID + j], red[j] + red[j + 128]);
}

// ---------------- head ----------------
__global__ void k_head(const float* __restrict__ pooled, const int* __restrict__ gstart,
                       const float* __restrict__ Wfc, const float* __restrict__ bfc,
                       float* __restrict__ out) {
    int g = threadIdx.x;
    if (g >= N_GRAPHS) return;
    float inv = 1.0f / fmaxf((float)(gstart[g + 1] - gstart[g]), 1.0f);
    float l0 = bfc[0], l1 = bfc[1];
    for (int j = 0; j < HID; ++j) {
        float p = pooled[g * HID + j] * inv;
        l0 += p * Wfc[j * OUT_DIM + 0];
        l1 += p * Wfc[j * OUT_DIM + 1];
    }
    float m = fmaxf(l0, l1);
    float lse = m + logf(expf(l0 - m) + expf(l1 - m));
    out[g * OUT_DIM + 0] = l0 - lse;
    out[g * OUT_DIM + 1] = l1 - lse;
}

extern "C" void kernel_launch(void* const* d_in, const int* in_sizes, int n_in,
                              void* d_out, int out_size, void* d_ws, size_t ws_size,
                              hipStream_t stream) {
    const float* x   = (const float*)d_in[0];
    const float* W1  = (const float*)d_in[1];
    const float* b1  = (const float*)d_in[2];
    const float* W2  = (const float*)d_in[3];
    const float* b2  = (const float*)d_in[4];
    const float* Wfc = (const float*)d_in[5];
    const float* bfc = (const float*)d_in[6];
    const int* ei    = (const int*)d_in[7];   // [2, E]
    const int* batch = (const int*)d_in[8];
    const int* src = ei;
    const int* dst = ei + N_EDGES;
    float* out = (float*)d_out;

    // workspace layout
    float* bufA = (float*)d_ws;                    // agg outputs (bf16) / bucket overlay
    float* bufB = bufA + (long long)N_NODES * HID; // xs/hs bf16, gemm2 f32 out
    int* bsrc = (int*)bufA;                        // NBUK*BCAP (dead before agg1)
    int* bdst = bsrc + NBUK * BCAP;                // NBUK*BCAP
    ushort* agg1o = (ushort*)bufA;                 // N*64 bf16
    ushort* agg2o = (ushort*)bufA;                 // N*128 bf16
    ushort* xs = (ushort*)bufB;                    // N*64 bf16
    ushort* hs = (ushort*)bufB;                    // N*128 bf16
    int* row_start = (int*)(bufB + (long long)N_NODES * HID);  // N+1
    float* dinv = (float*)(row_start + N_NODES + 1);  // N
    int* gcur = (int*)(dinv + N_NODES);            // NBUK
    int* bstart = gcur + NBUK;                     // NBUK
    int* gstart = bstart + NBUK;                   // N_GRAPHS+1
    int* csr = gstart + (N_GRAPHS + 1);            // E
    float* pooled = (float*)(csr + N_EDGES);       // G*HID

    // ----- CSR build (bucketed, no per-edge global atomics) -----
    k_gcur_init<<<(NBUK + 255) / 256, 256, 0, stream>>>(gcur);
    k_pass1<<<NBLK_P1, 256, 0, stream>>>(src, dst, gcur, bsrc, bdst);
    k_bscan<<<1, 512, 0, stream>>>(gcur, bstart, row_start);
    k_pass2<<<NBUK, 256, 0, stream>>>(gcur, bstart, bsrc, bdst, row_start, dinv, csr);
    k_gbound<<<(N_NODES + 255) / 256, 256, 0, stream>>>(batch, gstart);

    const int NGBLK = (N_NODES + 63) / 64;

    // ----- layer 1 -----
    k_xscale<<<(N_NODES * 16 + 255) / 256, 256, 0, stream>>>(x, dinv, xs);
    k_agg1<<<N_NODES / 8, 256, 0, stream>>>(row_start, csr, (const uint32*)xs, dinv,
                                            (uint32*)agg1o);
    k_gemm_mfma<IN_DIM, 1><<<NGBLK, 256, 0, stream>>>(agg1o, W1, b1, dinv, hs);

    // ----- layer 2 -----
    k_agg2<<<N_NODES / 8, 256, 0, stream>>>(row_start, csr, (const uint2*)hs, dinv,
                                            (uint2*)agg2o);
    k_gemm_mfma<HID, 0><<<NGBLK, 256, 0, stream>>>(agg2o, W2, b2, dinv, bufB);

    // ----- pool + head -----
    hipMemsetAsync(pooled, 0, N_GRAPHS * HID * sizeof(float), stream);
    k_pool<<<N_GRAPHS * MAXCH, 256, 0, stream>>>(bufB, gstart, pooled);
    k_head<<<1, 64, 0, stream>>>(pooled, gstart, Wfc, bfc, out);
}

// Round 10
// 230.744 us; speedup vs baseline: 2.2027x; 1.0495x over previous
//
#include <hip/hip_runtime.h>
#include <math.h>

#define N_NODES 100000
#define N_EDGES 1600000
#define IN_DIM 64
#define HID 128
#define OUT_DIM 2
#define N_GRAPHS 64

#define NBUK ((N_NODES + 255) / 256)         // 391 buckets of 256 nodes
#define BCAP 4608                            // slots per bucket (mean 4096, 8 sigma)
#define E4 (N_EDGES / 4)                     // 400000 int4 edge groups
#define NBLK_P1 ((E4 + 1023) / 1024)         // 391

#define PCHUNK 256                           // pool rows per block
#define MAXCH 8                              // max chunks per graph

typedef unsigned int uint32;
typedef __attribute__((ext_vector_type(8))) short bf16x8;
typedef __attribute__((ext_vector_type(4))) float f32x4;

static __device__ __forceinline__ ushort f2bf(float f) {
    uint32 u = __float_as_uint(f);
    uint32 r = (u + 0x7fff + ((u >> 16) & 1)) >> 16;  // RNE
    return (ushort)r;
}
static __device__ __forceinline__ float bf2f(uint32 u) {
    return __uint_as_float(u << 16);
}
static __device__ __forceinline__ float bflo(uint32 u) { return bf2f(u & 0xffffu); }
static __device__ __forceinline__ float bfhi(uint32 u) { return bf2f(u >> 16); }

// ---------------- bucketed CSR build ----------------
__global__ __launch_bounds__(256) void k_gcur_init(int* __restrict__ gcur) {
    int i = blockIdx.x * 256 + threadIdx.x;
    if (i < NBUK) gcur[i] = i * BCAP;
}

// pass 1: 1024 threads, 4 edges/thread in registers, one global atomic per (block,bucket)
__global__ __launch_bounds__(1024) void k_pass1(const int4* __restrict__ src4,
                                                const int4* __restrict__ dst4,
                                                int* __restrict__ gcur,
                                                int* __restrict__ bsrc,
                                                int* __restrict__ bdst) {
    __shared__ int hist[NBUK];
    __shared__ int base[NBUK];
    int tid = threadIdx.x;
    if (tid < NBUK) hist[tid] = 0;
    __syncthreads();
    int i4 = blockIdx.x * 1024 + tid;
    bool act = i4 < E4;
    int4 d = {0, 0, 0, 0}, s = {0, 0, 0, 0};
    if (act) {
        d = dst4[i4];
        s = src4[i4];
        atomicAdd(&hist[d.x >> 8], 1);
        atomicAdd(&hist[d.y >> 8], 1);
        atomicAdd(&hist[d.z >> 8], 1);
        atomicAdd(&hist[d.w >> 8], 1);
    }
    __syncthreads();
    if (tid < NBUK) {
        int c = hist[tid];
        base[tid] = c ? atomicAdd(&gcur[tid], c) : 0;
        hist[tid] = 0;
    }
    __syncthreads();
    if (act) {
        int b0 = d.x >> 8, r0 = atomicAdd(&hist[b0], 1);
        int b1 = d.y >> 8, r1 = atomicAdd(&hist[b1], 1);
        int b2 = d.z >> 8, r2 = atomicAdd(&hist[b2], 1);
        int b3 = d.w >> 8, r3 = atomicAdd(&hist[b3], 1);
        int sl0 = base[b0] + r0;
        int sl1 = base[b1] + r1;
        int sl2 = base[b2] + r2;
        int sl3 = base[b3] + r3;
        bsrc[sl0] = s.x; bdst[sl0] = d.x;
        bsrc[sl1] = s.y; bdst[sl1] = d.y;
        bsrc[sl2] = s.z; bdst[sl2] = d.z;
        bsrc[sl3] = s.w; bdst[sl3] = d.w;
    }
}

__global__ __launch_bounds__(512) void k_bscan(const int* __restrict__ gcur,
                                               int* __restrict__ bstart,
                                               int* __restrict__ row_start) {
    __shared__ int s[512];
    int t = threadIdx.x;
    int v = (t < NBUK) ? (gcur[t] - t * BCAP) : 0;
    s[t] = v;
    __syncthreads();
    for (int off = 1; off < 512; off <<= 1) {
        int u = (t >= off) ? s[t - off] : 0;
        __syncthreads();
        s[t] += u;
        __syncthreads();
    }
    if (t < NBUK) bstart[t] = s[t] - v;
    if (t == 0) row_start[N_NODES] = N_EDGES;
}

// pass 2: 1024 threads, per-bucket counting sort. No global atomics.
__global__ __launch_bounds__(1024) void k_pass2(const int* __restrict__ gcur,
                                                const int* __restrict__ bstart,
                                                const int* __restrict__ bsrc,
                                                const int* __restrict__ bdst,
                                                int* __restrict__ row_start,
                                                float* __restrict__ dinv,
                                                int* __restrict__ csr) {
    __shared__ int cnt[256];
    __shared__ int sc[256];
    __shared__ int lst[256];
    int b = blockIdx.x;
    int tid = threadIdx.x;
    int node0 = b * 256;
    int nloc = N_NODES - node0;
    if (nloc > 256) nloc = 256;
    int bbase = b * BCAP;
    int Eb = gcur[b] - bbase;

    if (tid < 256) cnt[tid] = 0;
    __syncthreads();
    for (int i = tid; i < Eb; i += 1024) atomicAdd(&cnt[bdst[bbase + i] & 255], 1);
    __syncthreads();
    int v = 0;
    if (tid < 256) {
        v = cnt[tid];
        sc[tid] = v;
    }
    __syncthreads();
    for (int off = 1; off < 256; off <<= 1) {
        int u = 0;
        if (tid < 256 && tid >= off) u = sc[tid - off];
        __syncthreads();
        if (tid < 256) sc[tid] += u;
        __syncthreads();
    }
    int gb = bstart[b];
    if (tid < 256) {
        int excl = sc[tid] - v;
        lst[tid] = excl;
        if (tid < nloc) {
            row_start[node0 + tid] = gb + excl;
            dinv[node0 + tid] = rsqrtf((float)(v + 1));  // +1 self loop
        }
        cnt[tid] = 0;
    }
    __syncthreads();
    for (int i = tid; i < Eb; i += 1024) {
        int d = bdst[bbase + i];
        int s = bsrc[bbase + i];
        int dl = d & 255;
        int r = atomicAdd(&cnt[dl], 1);
        csr[gb + lst[dl] + r] = s;
    }
}

// ---------------- graph boundaries from sorted batch ----------------
__global__ __launch_bounds__(256) void k_gbound(const int* __restrict__ batch,
                                                int* __restrict__ gstart) {
    int n = blockIdx.x * 256 + threadIdx.x;
    if (n >= N_NODES) return;
    if (n == 0) {
        for (int g = 0; g <= batch[0]; ++g) gstart[g] = 0;
    } else {
        int a = batch[n - 1], b = batch[n];
        for (int g = a + 1; g <= b; ++g) gstart[g] = n;
    }
    if (n == N_NODES - 1) {
        for (int g = batch[n] + 1; g <= N_GRAPHS; ++g) gstart[g] = N_NODES;
    }
}

// ---------------- pre-scale x by dinv -> bf16 ----------------
__global__ __launch_bounds__(256) void k_xscale(const float* __restrict__ x,
                                                const float* __restrict__ dinv,
                                                ushort* __restrict__ xs) {
    int idx = blockIdx.x * 256 + threadIdx.x;
    if (idx >= N_NODES * 16) return;
    float d = dinv[idx >> 4];
    float4 v = ((const float4*)x)[idx];
    ushort4 o;
    o.x = f2bf(v.x * d);
    o.y = f2bf(v.y * d);
    o.z = f2bf(v.z * d);
    o.w = f2bf(v.w * d);
    ((ushort4*)xs)[idx] = o;
}

// ---------------- aggregation (gather, CSR, bf16 in AND out) ----------------
__global__ __launch_bounds__(256) void k_agg1(const int* __restrict__ row_start,
                                              const int* __restrict__ csr,
                                              const uint32* __restrict__ xs,
                                              const float* __restrict__ dinv,
                                              uint32* __restrict__ outb) {
    int d = blockIdx.x * 8 + (threadIdx.x >> 5);
    int l = threadIdx.x & 31;
    float dd = dinv[d];
    uint32 u = xs[(long long)d * 32 + l];
    float a0 = bflo(u), a1 = bfhi(u);
    int e = row_start[d];
    int eend = row_start[d + 1];
    for (; e + 3 < eend; e += 4) {
        int s0 = csr[e], s1 = csr[e + 1], s2 = csr[e + 2], s3 = csr[e + 3];
        uint32 w0 = xs[(long long)s0 * 32 + l];
        uint32 w1 = xs[(long long)s1 * 32 + l];
        uint32 w2 = xs[(long long)s2 * 32 + l];
        uint32 w3 = xs[(long long)s3 * 32 + l];
        a0 += bflo(w0) + bflo(w1) + bflo(w2) + bflo(w3);
        a1 += bfhi(w0) + bfhi(w1) + bfhi(w2) + bfhi(w3);
    }
    for (; e < eend; ++e) {
        uint32 w = xs[(long long)csr[e] * 32 + l];
        a0 += bflo(w);
        a1 += bfhi(w);
    }
    outb[(long long)d * 32 + l] = (uint32)f2bf(a0 * dd) | ((uint32)f2bf(a1 * dd) << 16);
}

__global__ __launch_bounds__(256) void k_agg2(const int* __restrict__ row_start,
                                              const int* __restrict__ csr,
                                              const uint2* __restrict__ hs,
                                              const float* __restrict__ dinv,
                                              uint2* __restrict__ outb) {
    int d = blockIdx.x * 8 + (threadIdx.x >> 5);
    int l = threadIdx.x & 31;
    float dd = dinv[d];
    uint2 u = hs[(long long)d * 32 + l];
    float a0 = bflo(u.x), a1 = bfhi(u.x), a2 = bflo(u.y), a3 = bfhi(u.y);
    int e = row_start[d];
    int eend = row_start[d + 1];
    for (; e + 3 < eend; e += 4) {
        int s0 = csr[e], s1 = csr[e + 1], s2 = csr[e + 2], s3 = csr[e + 3];
        uint2 w0 = hs[(long long)s0 * 32 + l];
        uint2 w1 = hs[(long long)s1 * 32 + l];
        uint2 w2 = hs[(long long)s2 * 32 + l];
        uint2 w3 = hs[(long long)s3 * 32 + l];
        a0 += bflo(w0.x) + bflo(w1.x) + bflo(w2.x) + bflo(w3.x);
        a1 += bfhi(w0.x) + bfhi(w1.x) + bfhi(w2.x) + bfhi(w3.x);
        a2 += bflo(w0.y) + bflo(w1.y) + bflo(w2.y) + bflo(w3.y);
        a3 += bfhi(w0.y) + bfhi(w1.y) + bfhi(w2.y) + bfhi(w3.y);
    }
    for (; e < eend; ++e) {
        uint2 w = hs[(long long)csr[e] * 32 + l];
        a0 += bflo(w.x);
        a1 += bfhi(w.x);
        a2 += bflo(w.y);
        a3 += bfhi(w.y);
    }
    uint2 o;
    o.x = (uint32)f2bf(a0 * dd) | ((uint32)f2bf(a1 * dd) << 16);
    o.y = (uint32)f2bf(a2 * dd) | ((uint32)f2bf(a3 * dd) << 16);
    outb[(long long)d * 32 + l] = o;
}

// ---------------- MFMA GEMM: out[N,128] = relu(A[N,K](bf16) @ W[K,128] + b) ----------------
template <int K, int OUT_BF>
__global__ __launch_bounds__(256) void k_gemm_mfma(const ushort* __restrict__ A,
                                                   const float* __restrict__ W,
                                                   const float* __restrict__ bias,
                                                   const float* __restrict__ dinv,
                                                   void* __restrict__ outv) {
    constexpr int KSTEPS = K / 32;
    constexpr int LDSK = K + 8;          // pad: col stride 4 banks -> 2-way (free)
    __shared__ ushort WT[128 * LDSK];    // [col][k] bf16
    int tid = threadIdx.x;
    for (int idx = tid; idx < K * 128; idx += 256) {
        int k = idx >> 7, c = idx & 127;
        WT[c * LDSK + k] = f2bf(W[idx]);
    }
    __syncthreads();

    int w = tid >> 6, l = tid & 63;
    int row0 = blockIdx.x * 64 + w * 16;
    int arow = row0 + (l & 15);
    if (arow > N_NODES - 1) arow = N_NODES - 1;
    int koff = (l >> 4) * 8;

    bf16x8 af[KSTEPS];
#pragma unroll
    for (int ks = 0; ks < KSTEPS; ++ks)
        af[ks] = *(const bf16x8*)(A + (long long)arow * K + ks * 32 + koff);

    f32x4 acc[8];
#pragma unroll
    for (int t = 0; t < 8; ++t) acc[t] = (f32x4){0.f, 0.f, 0.f, 0.f};

#pragma unroll
    for (int ks = 0; ks < KSTEPS; ++ks) {
#pragma unroll
        for (int t = 0; t < 8; ++t) {
            int c = t * 16 + (l & 15);
            bf16x8 bf = *(const bf16x8*)&WT[c * LDSK + ks * 32 + koff];
            acc[t] = __builtin_amdgcn_mfma_f32_16x16x32_bf16(af[ks], bf, acc[t], 0, 0, 0);
        }
    }

    int rbase = row0 + ((l >> 4) << 2);
#pragma unroll
    for (int t = 0; t < 8; ++t) {
        int col = t * 16 + (l & 15);
        float bb = bias[col];
#pragma unroll
        for (int i = 0; i < 4; ++i) {
            int row = rbase + i;
            if (row < N_NODES) {
                float v = acc[t][i] + bb;
                v = v > 0.f ? v : 0.f;
                if (OUT_BF) {
                    ((ushort*)outv)[(long long)row * HID + col] = f2bf(v * dinv[row]);
                } else {
                    ((float*)outv)[(long long)row * HID + col] = v;
                }
            }
        }
    }
}

// ---------------- pooling: one block per (graph, chunk) ----------------
__global__ __launch_bounds__(256) void k_pool(const float* __restrict__ h,
                                              const int* __restrict__ gstart,
                                              float* __restrict__ pooled) {
    int g = blockIdx.x >> 3;   // / MAXCH
    int c = blockIdx.x & (MAXCH - 1);
    int r0 = gstart[g] + c * PCHUNK;
    int r1 = gstart[g + 1];
    if (r0 >= r1) return;
    int rend = r0 + PCHUNK;
    if (rend > r1) rend = r1;
    int j = threadIdx.x & 127;
    int half = threadIdx.x >> 7;
    float a0 = 0.f, a1 = 0.f, a2 = 0.f, a3 = 0.f;
    int r = r0 + half;
    for (; r + 6 < rend; r += 8) {
        a0 += h[(long long)r * HID + j];
        a1 += h[(long long)(r + 2) * HID + j];
        a2 += h[(long long)(r + 4) * HID + j];
        a3 += h[(long long)(r + 6) * HID + j];
    }
    for (; r < rend; r += 2) a0 += h[(long long)r * HID + j];
    __shared__ float red[256];
    red[threadIdx.x] = (a0 + a1) + (a2 + a3);
    __syncthreads();
    if (half == 0) atomicAdd(&pooled[g * HID + j], red[j] + red[j + 128]);
}

// ---------------- head ----------------
__global__ void k_head(const float* __restrict__ pooled, const int* __restrict__ gstart,
                       const float* __restrict__ Wfc, const float* __restrict__ bfc,
                       float* __restrict__ out) {
    int g = threadIdx.x;
    if (g >= N_GRAPHS) return;
    float inv = 1.0f / fmaxf((float)(gstart[g + 1] - gstart[g]), 1.0f);
    float l0 = bfc[0], l1 = bfc[1];
    for (int j = 0; j < HID; ++j) {
        float p = pooled[g * HID + j] * inv;
        l0 += p * Wfc[j * OUT_DIM + 0];
        l1 += p * Wfc[j * OUT_DIM + 1];
    }
    float m = fmaxf(l0, l1);
    float lse = m + logf(expf(l0 - m) + expf(l1 - m));
    out[g * OUT_DIM + 0] = l0 - lse;
    out[g * OUT_DIM + 1] = l1 - lse;
}

extern "C" void kernel_launch(void* const* d_in, const int* in_sizes, int n_in,
                              void* d_out, int out_size, void* d_ws, size_t ws_size,
                              hipStream_t stream) {
    const float* x   = (const float*)d_in[0];
    const float* W1  = (const float*)d_in[1];
    const float* b1  = (const float*)d_in[2];
    const float* W2  = (const float*)d_in[3];
    const float* b2  = (const float*)d_in[4];
    const float* Wfc = (const float*)d_in[5];
    const float* bfc = (const float*)d_in[6];
    const int* ei    = (const int*)d_in[7];   // [2, E]
    const int* batch = (const int*)d_in[8];
    const int* src = ei;
    const int* dst = ei + N_EDGES;
    float* out = (float*)d_out;

    // workspace layout
    float* bufA = (float*)d_ws;                    // agg outputs (bf16) / bucket overlay
    float* bufB = bufA + (long long)N_NODES * HID; // xs/hs bf16, gemm2 f32 out
    int* bsrc = (int*)bufA;                        // NBUK*BCAP (dead before agg1)
    int* bdst = bsrc + NBUK * BCAP;                // NBUK*BCAP
    ushort* agg1o = (ushort*)bufA;                 // N*64 bf16
    ushort* agg2o = (ushort*)bufA;                 // N*128 bf16
    ushort* xs = (ushort*)bufB;                    // N*64 bf16
    ushort* hs = (ushort*)bufB;                    // N*128 bf16
    int* row_start = (int*)(bufB + (long long)N_NODES * HID);  // N+1
    float* dinv = (float*)(row_start + N_NODES + 1);  // N
    int* gcur = (int*)(dinv + N_NODES);            // NBUK
    int* bstart = gcur + NBUK;                     // NBUK
    int* gstart = bstart + NBUK;                   // N_GRAPHS+1
    int* csr = gstart + (N_GRAPHS + 1);            // E
    float* pooled = (float*)(csr + N_EDGES);       // G*HID

    // ----- CSR build (bucketed, wide blocks) -----
    k_gcur_init<<<(NBUK + 255) / 256, 256, 0, stream>>>(gcur);
    k_pass1<<<NBLK_P1, 1024, 0, stream>>>((const int4*)src, (const int4*)dst, gcur, bsrc, bdst);
    k_bscan<<<1, 512, 0, stream>>>(gcur, bstart, row_start);
    k_pass2<<<NBUK, 1024, 0, stream>>>(gcur, bstart, bsrc, bdst, row_start, dinv, csr);
    k_gbound<<<(N_NODES + 255) / 256, 256, 0, stream>>>(batch, gstart);

    const int NGBLK = (N_NODES + 63) / 64;

    // ----- layer 1 -----
    k_xscale<<<(N_NODES * 16 + 255) / 256, 256, 0, stream>>>(x, dinv, xs);
    k_agg1<<<N_NODES / 8, 256, 0, stream>>>(row_start, csr, (const uint32*)xs, dinv,
                                            (uint32*)agg1o);
    k_gemm_mfma<IN_DIM, 1><<<NGBLK, 256, 0, stream>>>(agg1o, W1, b1, dinv, hs);

    // ----- layer 2 -----
    k_agg2<<<N_NODES / 8, 256, 0, stream>>>(row_start, csr, (const uint2*)hs, dinv,
                                            (uint2*)agg2o);
    k_gemm_mfma<HID, 0><<<NGBLK, 256, 0, stream>>>(agg2o, W2, b2, dinv, bufB);

    // ----- pool + head -----
    hipMemsetAsync(pooled, 0, N_GRAPHS * HID * sizeof(float), stream);
    k_pool<<<N_GRAPHS * MAXCH, 256, 0, stream>>>(bufB, gstart, pooled);
    k_head<<<1, 64, 0, stream>>>(pooled, gstart, Wfc, bfc, out);
}

// Round 11
// 218.341 us; speedup vs baseline: 2.3278x; 1.0568x over previous
//
#include <hip/hip_runtime.h>
#include <math.h>

#define N_NODES 100000
#define N_EDGES 1600000
#define IN_DIM 64
#define HID 128
#define OUT_DIM 2
#define N_GRAPHS 64

#define NBUK ((N_NODES + 255) / 256)         // 391 buckets of 256 nodes
#define BCAP 4608                            // slots per bucket (mean 4096, 8 sigma)
#define E4 (N_EDGES / 4)                     // 400000 int4 edge groups
#define NBLK_P1 ((E4 + 1023) / 1024)         // 391

#define PCHUNK 256                           // pool rows per block
#define MAXCH 8                              // max chunks per graph

typedef unsigned int uint32;
typedef __attribute__((ext_vector_type(8))) short bf16x8;
typedef __attribute__((ext_vector_type(4))) float f32x4;

static __device__ __forceinline__ ushort f2bf(float f) {
    uint32 u = __float_as_uint(f);
    uint32 r = (u + 0x7fff + ((u >> 16) & 1)) >> 16;  // RNE
    return (ushort)r;
}
static __device__ __forceinline__ float bf2f(uint32 u) {
    return __uint_as_float(u << 16);
}
static __device__ __forceinline__ float bflo(uint32 u) { return bf2f(u & 0xffffu); }
static __device__ __forceinline__ float bfhi(uint32 u) { return bf2f(u >> 16); }

// ---------------- bucketed CSR build ----------------
// gcur holds per-bucket COUNTS (memset 0); slot base = bucket*BCAP + count offset.
__global__ __launch_bounds__(1024) void k_pass1(const int4* __restrict__ src4,
                                                const int4* __restrict__ dst4,
                                                int* __restrict__ gcur,
                                                int* __restrict__ bsrc,
                                                int* __restrict__ bdst) {
    __shared__ int hist[NBUK];
    __shared__ int base[NBUK];
    int tid = threadIdx.x;
    if (tid < NBUK) hist[tid] = 0;
    __syncthreads();
    int i4 = blockIdx.x * 1024 + tid;
    bool act = i4 < E4;
    int4 d = {0, 0, 0, 0}, s = {0, 0, 0, 0};
    if (act) {
        d = dst4[i4];
        s = src4[i4];
        atomicAdd(&hist[d.x >> 8], 1);
        atomicAdd(&hist[d.y >> 8], 1);
        atomicAdd(&hist[d.z >> 8], 1);
        atomicAdd(&hist[d.w >> 8], 1);
    }
    __syncthreads();
    if (tid < NBUK) {
        int c = hist[tid];
        base[tid] = tid * BCAP + (c ? atomicAdd(&gcur[tid], c) : 0);
        hist[tid] = 0;
    }
    __syncthreads();
    if (act) {
        int b0 = d.x >> 8, r0 = atomicAdd(&hist[b0], 1);
        int b1 = d.y >> 8, r1 = atomicAdd(&hist[b1], 1);
        int b2 = d.z >> 8, r2 = atomicAdd(&hist[b2], 1);
        int b3 = d.w >> 8, r3 = atomicAdd(&hist[b3], 1);
        int sl0 = base[b0] + r0;
        int sl1 = base[b1] + r1;
        int sl2 = base[b2] + r2;
        int sl3 = base[b3] + r3;
        bsrc[sl0] = s.x; bdst[sl0] = d.x;
        bsrc[sl1] = s.y; bdst[sl1] = d.y;
        bsrc[sl2] = s.z; bdst[sl2] = d.z;
        bsrc[sl3] = s.w; bdst[sl3] = d.w;
    }
}

__global__ __launch_bounds__(512) void k_bscan(const int* __restrict__ gcur,
                                               int* __restrict__ bstart,
                                               int* __restrict__ row_start) {
    __shared__ int s[512];
    int t = threadIdx.x;
    int v = (t < NBUK) ? gcur[t] : 0;
    s[t] = v;
    __syncthreads();
    for (int off = 1; off < 512; off <<= 1) {
        int u = (t >= off) ? s[t - off] : 0;
        __syncthreads();
        s[t] += u;
        __syncthreads();
    }
    if (t < NBUK) bstart[t] = s[t] - v;
    if (t == 0) row_start[N_NODES] = N_EDGES;
}

// pass 2: per-bucket counting sort + fused xscale (xs = bf16(dinv*x)). No global atomics.
__global__ __launch_bounds__(1024) void k_pass2(const int* __restrict__ gcur,
                                                const int* __restrict__ bstart,
                                                const int* __restrict__ bsrc,
                                                const int* __restrict__ bdst,
                                                const float* __restrict__ x,
                                                int* __restrict__ row_start,
                                                float* __restrict__ dinv,
                                                int* __restrict__ csr,
                                                ushort* __restrict__ xs) {
    __shared__ int cnt[256];
    __shared__ int sc[256];
    __shared__ int lst[256];
    __shared__ float sdinv[256];
    int b = blockIdx.x;
    int tid = threadIdx.x;
    int node0 = b * 256;
    int nloc = N_NODES - node0;
    if (nloc > 256) nloc = 256;
    int bbase = b * BCAP;
    int Eb = gcur[b];

    if (tid < 256) cnt[tid] = 0;
    __syncthreads();
    for (int i = tid; i < Eb; i += 1024) atomicAdd(&cnt[bdst[bbase + i] & 255], 1);
    __syncthreads();
    int v = 0;
    if (tid < 256) {
        v = cnt[tid];
        sc[tid] = v;
    }
    __syncthreads();
    for (int off = 1; off < 256; off <<= 1) {
        int u = 0;
        if (tid < 256 && tid >= off) u = sc[tid - off];
        __syncthreads();
        if (tid < 256) sc[tid] += u;
        __syncthreads();
    }
    int gb = bstart[b];
    if (tid < 256) {
        int excl = sc[tid] - v;
        lst[tid] = excl;
        if (tid < nloc) {
            float dv = rsqrtf((float)(v + 1));  // +1 self loop
            row_start[node0 + tid] = gb + excl;
            dinv[node0 + tid] = dv;
            sdinv[tid] = dv;
        }
        cnt[tid] = 0;
    }
    __syncthreads();
    for (int i = tid; i < Eb; i += 1024) {
        int d = bdst[bbase + i];
        int s = bsrc[bbase + i];
        int dl = d & 255;
        int r = atomicAdd(&cnt[dl], 1);
        csr[gb + lst[dl] + r] = s;
    }
    // fused xscale for this block's 256 nodes
    int f0 = node0 * 16;
    int f1 = (node0 + nloc) * 16;
    for (int idx = f0 + tid; idx < f1; idx += 1024) {
        float dv = sdinv[(idx >> 4) - node0];
        float4 vv = ((const float4*)x)[idx];
        ushort4 o;
        o.x = f2bf(vv.x * dv);
        o.y = f2bf(vv.y * dv);
        o.z = f2bf(vv.z * dv);
        o.w = f2bf(vv.w * dv);
        ((ushort4*)xs)[idx] = o;
    }
}

// ---------------- graph boundaries from sorted batch ----------------
__global__ __launch_bounds__(256) void k_gbound(const int* __restrict__ batch,
                                                int* __restrict__ gstart) {
    int n = blockIdx.x * 256 + threadIdx.x;
    if (n >= N_NODES) return;
    if (n == 0) {
        for (int g = 0; g <= batch[0]; ++g) gstart[g] = 0;
    } else {
        int a = batch[n - 1], b = batch[n];
        for (int g = a + 1; g <= b; ++g) gstart[g] = n;
    }
    if (n == N_NODES - 1) {
        for (int g = batch[n] + 1; g <= N_GRAPHS; ++g) gstart[g] = N_NODES;
    }
}

// ---------------- aggregation (gather, CSR, bf16 in AND out, 8-deep MLP) ----------------
__global__ __launch_bounds__(256) void k_agg1(const int* __restrict__ row_start,
                                              const int* __restrict__ csr,
                                              const uint32* __restrict__ xs,
                                              const float* __restrict__ dinv,
                                              uint32* __restrict__ outb) {
    int d = blockIdx.x * 8 + (threadIdx.x >> 5);
    int l = threadIdx.x & 31;
    float dd = dinv[d];
    uint32 u = xs[(long long)d * 32 + l];
    float a0 = bflo(u), a1 = bfhi(u);
    int e = row_start[d];
    int eend = row_start[d + 1];
    for (; e + 7 < eend; e += 8) {
        int s0 = csr[e], s1 = csr[e + 1], s2 = csr[e + 2], s3 = csr[e + 3];
        int s4 = csr[e + 4], s5 = csr[e + 5], s6 = csr[e + 6], s7 = csr[e + 7];
        uint32 w0 = xs[(long long)s0 * 32 + l];
        uint32 w1 = xs[(long long)s1 * 32 + l];
        uint32 w2 = xs[(long long)s2 * 32 + l];
        uint32 w3 = xs[(long long)s3 * 32 + l];
        uint32 w4 = xs[(long long)s4 * 32 + l];
        uint32 w5 = xs[(long long)s5 * 32 + l];
        uint32 w6 = xs[(long long)s6 * 32 + l];
        uint32 w7 = xs[(long long)s7 * 32 + l];
        a0 += ((bflo(w0) + bflo(w1)) + (bflo(w2) + bflo(w3))) +
              ((bflo(w4) + bflo(w5)) + (bflo(w6) + bflo(w7)));
        a1 += ((bfhi(w0) + bfhi(w1)) + (bfhi(w2) + bfhi(w3))) +
              ((bfhi(w4) + bfhi(w5)) + (bfhi(w6) + bfhi(w7)));
    }
    for (; e + 3 < eend; e += 4) {
        int s0 = csr[e], s1 = csr[e + 1], s2 = csr[e + 2], s3 = csr[e + 3];
        uint32 w0 = xs[(long long)s0 * 32 + l];
        uint32 w1 = xs[(long long)s1 * 32 + l];
        uint32 w2 = xs[(long long)s2 * 32 + l];
        uint32 w3 = xs[(long long)s3 * 32 + l];
        a0 += (bflo(w0) + bflo(w1)) + (bflo(w2) + bflo(w3));
        a1 += (bfhi(w0) + bfhi(w1)) + (bfhi(w2) + bfhi(w3));
    }
    for (; e < eend; ++e) {
        uint32 w = xs[(long long)csr[e] * 32 + l];
        a0 += bflo(w);
        a1 += bfhi(w);
    }
    outb[(long long)d * 32 + l] = (uint32)f2bf(a0 * dd) | ((uint32)f2bf(a1 * dd) << 16);
}

__global__ __launch_bounds__(256) void k_agg2(const int* __restrict__ row_start,
                                              const int* __restrict__ csr,
                                              const uint2* __restrict__ hs,
                                              const float* __restrict__ dinv,
                                              uint2* __restrict__ outb) {
    int d = blockIdx.x * 8 + (threadIdx.x >> 5);
    int l = threadIdx.x & 31;
    float dd = dinv[d];
    uint2 u = hs[(long long)d * 32 + l];
    float a0 = bflo(u.x), a1 = bfhi(u.x), a2 = bflo(u.y), a3 = bfhi(u.y);
    int e = row_start[d];
    int eend = row_start[d + 1];
    for (; e + 7 < eend; e += 8) {
        int s0 = csr[e], s1 = csr[e + 1], s2 = csr[e + 2], s3 = csr[e + 3];
        int s4 = csr[e + 4], s5 = csr[e + 5], s6 = csr[e + 6], s7 = csr[e + 7];
        uint2 w0 = hs[(long long)s0 * 32 + l];
        uint2 w1 = hs[(long long)s1 * 32 + l];
        uint2 w2 = hs[(long long)s2 * 32 + l];
        uint2 w3 = hs[(long long)s3 * 32 + l];
        uint2 w4 = hs[(long long)s4 * 32 + l];
        uint2 w5 = hs[(long long)s5 * 32 + l];
        uint2 w6 = hs[(long long)s6 * 32 + l];
        uint2 w7 = hs[(long long)s7 * 32 + l];
        a0 += ((bflo(w0.x) + bflo(w1.x)) + (bflo(w2.x) + bflo(w3.x))) +
              ((bflo(w4.x) + bflo(w5.x)) + (bflo(w6.x) + bflo(w7.x)));
        a1 += ((bfhi(w0.x) + bfhi(w1.x)) + (bfhi(w2.x) + bfhi(w3.x))) +
              ((bfhi(w4.x) + bfhi(w5.x)) + (bfhi(w6.x) + bfhi(w7.x)));
        a2 += ((bflo(w0.y) + bflo(w1.y)) + (bflo(w2.y) + bflo(w3.y))) +
              ((bflo(w4.y) + bflo(w5.y)) + (bflo(w6.y) + bflo(w7.y)));
        a3 += ((bfhi(w0.y) + bfhi(w1.y)) + (bfhi(w2.y) + bfhi(w3.y))) +
              ((bfhi(w4.y) + bfhi(w5.y)) + (bfhi(w6.y) + bfhi(w7.y)));
    }
    for (; e + 3 < eend; e += 4) {
        int s0 = csr[e], s1 = csr[e + 1], s2 = csr[e + 2], s3 = csr[e + 3];
        uint2 w0 = hs[(long long)s0 * 32 + l];
        uint2 w1 = hs[(long long)s1 * 32 + l];
        uint2 w2 = hs[(long long)s2 * 32 + l];
        uint2 w3 = hs[(long long)s3 * 32 + l];
        a0 += (bflo(w0.x) + bflo(w1.x)) + (bflo(w2.x) + bflo(w3.x));
        a1 += (bfhi(w0.x) + bfhi(w1.x)) + (bfhi(w2.x) + bfhi(w3.x));
        a2 += (bflo(w0.y) + bflo(w1.y)) + (bflo(w2.y) + bflo(w3.y));
        a3 += (bfhi(w0.y) + bfhi(w1.y)) + (bfhi(w2.y) + bfhi(w3.y));
    }
    for (; e < eend; ++e) {
        uint2 w = hs[(long long)csr[e] * 32 + l];
        a0 += bflo(w.x);
        a1 += bfhi(w.x);
        a2 += bflo(w.y);
        a3 += bfhi(w.y);
    }
    uint2 o;
    o.x = (uint32)f2bf(a0 * dd) | ((uint32)f2bf(a1 * dd) << 16);
    o.y = (uint32)f2bf(a2 * dd) | ((uint32)f2bf(a3 * dd) << 16);
    outb[(long long)d * 32 + l] = o;
}

// ---------------- MFMA GEMM: out[N,128] = relu(A[N,K](bf16) @ W[K,128] + b) ----------------
// OUTM: 0 = f32, 1 = bf16 * dinv[row], 2 = bf16
template <int K, int OUTM>
__global__ __launch_bounds__(256) void k_gemm_mfma(const ushort* __restrict__ A,
                                                   const float* __restrict__ W,
                                                   const float* __restrict__ bias,
                                                   const float* __restrict__ dinv,
                                                   void* __restrict__ outv) {
    constexpr int KSTEPS = K / 32;
    constexpr int LDSK = K + 8;          // pad: col stride 4 banks -> 2-way (free)
    __shared__ ushort WT[128 * LDSK];    // [col][k] bf16
    int tid = threadIdx.x;
    for (int idx = tid; idx < K * 128; idx += 256) {
        int k = idx >> 7, c = idx & 127;
        WT[c * LDSK + k] = f2bf(W[idx]);
    }
    __syncthreads();

    int w = tid >> 6, l = tid & 63;
    int row0 = blockIdx.x * 64 + w * 16;
    int arow = row0 + (l & 15);
    if (arow > N_NODES - 1) arow = N_NODES - 1;
    int koff = (l >> 4) * 8;

    bf16x8 af[KSTEPS];
#pragma unroll
    for (int ks = 0; ks < KSTEPS; ++ks)
        af[ks] = *(const bf16x8*)(A + (long long)arow * K + ks * 32 + koff);

    f32x4 acc[8];
#pragma unroll
    for (int t = 0; t < 8; ++t) acc[t] = (f32x4){0.f, 0.f, 0.f, 0.f};

#pragma unroll
    for (int ks = 0; ks < KSTEPS; ++ks) {
#pragma unroll
        for (int t = 0; t < 8; ++t) {
            int c = t * 16 + (l & 15);
            bf16x8 bf = *(const bf16x8*)&WT[c * LDSK + ks * 32 + koff];
            acc[t] = __builtin_amdgcn_mfma_f32_16x16x32_bf16(af[ks], bf, acc[t], 0, 0, 0);
        }
    }

    int rbase = row0 + ((l >> 4) << 2);
#pragma unroll
    for (int t = 0; t < 8; ++t) {
        int col = t * 16 + (l & 15);
        float bb = bias[col];
#pragma unroll
        for (int i = 0; i < 4; ++i) {
            int row = rbase + i;
            if (row < N_NODES) {
                float v = acc[t][i] + bb;
                v = v > 0.f ? v : 0.f;
                if (OUTM == 1) {
                    ((ushort*)outv)[(long long)row * HID + col] = f2bf(v * dinv[row]);
                } else if (OUTM == 2) {
                    ((ushort*)outv)[(long long)row * HID + col] = f2bf(v);
                } else {
                    ((float*)outv)[(long long)row * HID + col] = v;
                }
            }
        }
    }
}

// ---------------- pooling (bf16 input): one block per (graph, chunk) ----------------
__global__ __launch_bounds__(256) void k_pool(const uint32* __restrict__ h2,
                                              const int* __restrict__ gstart,
                                              float* __restrict__ pooled) {
    int g = blockIdx.x >> 3;   // / MAXCH
    int c = blockIdx.x & (MAXCH - 1);
    int r0 = gstart[g] + c * PCHUNK;
    int r1 = gstart[g + 1];
    if (r0 >= r1) return;
    int rend = r0 + PCHUNK;
    if (rend > r1) rend = r1;
    int j = threadIdx.x & 63;   // col pair
    int q = threadIdx.x >> 6;   // 0..3
    float a0 = 0.f, a1 = 0.f, b0 = 0.f, b1 = 0.f;
    int r = r0 + q;
    for (; r + 4 < rend; r += 8) {
        uint32 u = h2[(long long)r * 64 + j];
        uint32 v = h2[(long long)(r + 4) * 64 + j];
        a0 += bflo(u);
        a1 += bfhi(u);
        b0 += bflo(v);
        b1 += bfhi(v);
    }
    for (; r < rend; r += 4) {
        uint32 u = h2[(long long)r * 64 + j];
        a0 += bflo(u);
        a1 += bfhi(u);
    }
    __shared__ float red[256][2];
    red[threadIdx.x][0] = a0 + b0;
    red[threadIdx.x][1] = a1 + b1;
    __syncthreads();
    if (q == 0) {
        float s0 = (red[j][0] + red[j + 64][0]) + (red[j + 128][0] + red[j + 192][0]);
        float s1 = (red[j][1] + red[j + 64][1]) + (red[j + 128][1] + red[j + 192][1]);
        atomicAdd(&pooled[g * HID + 2 * j], s0);
        atomicAdd(&pooled[g * HID + 2 * j + 1], s1);
    }
}

// ---------------- head: 4 lanes per graph ----------------
__global__ __launch_bounds__(256) void k_head(const float* __restrict__ pooled,
                                              const int* __restrict__ gstart,
                                              const float* __restrict__ Wfc,
                                              const float* __restrict__ bfc,
                                              float* __restrict__ out) {
    int t = threadIdx.x;
    int g = t >> 2, sub = t & 3;
    float inv = 1.0f / fmaxf((float)(gstart[g + 1] - gstart[g]), 1.0f);
    float l0 = 0.f, l1 = 0.f;
    for (int j = sub * 32; j < sub * 32 + 32; ++j) {
        float p = pooled[g * HID + j] * inv;
        l0 += p * Wfc[j * OUT_DIM + 0];
        l1 += p * Wfc[j * OUT_DIM + 1];
    }
    l0 += __shfl_xor(l0, 1);
    l1 += __shfl_xor(l1, 1);
    l0 += __shfl_xor(l0, 2);
    l1 += __shfl_xor(l1, 2);
    if (sub == 0) {
        l0 += bfc[0];
        l1 += bfc[1];
        float m = fmaxf(l0, l1);
        float lse = m + logf(expf(l0 - m) + expf(l1 - m));
        out[g * OUT_DIM + 0] = l0 - lse;
        out[g * OUT_DIM + 1] = l1 - lse;
    }
}

extern "C" void kernel_launch(void* const* d_in, const int* in_sizes, int n_in,
                              void* d_out, int out_size, void* d_ws, size_t ws_size,
                              hipStream_t stream) {
    const float* x   = (const float*)d_in[0];
    const float* W1  = (const float*)d_in[1];
    const float* b1  = (const float*)d_in[2];
    const float* W2  = (const float*)d_in[3];
    const float* b2  = (const float*)d_in[4];
    const float* Wfc = (const float*)d_in[5];
    const float* bfc = (const float*)d_in[6];
    const int* ei    = (const int*)d_in[7];   // [2, E]
    const int* batch = (const int*)d_in[8];
    const int* src = ei;
    const int* dst = ei + N_EDGES;
    float* out = (float*)d_out;

    // workspace layout
    float* bufA = (float*)d_ws;                    // agg outputs (bf16) / bucket overlay
    float* bufB = bufA + (long long)N_NODES * HID; // xs / hs / h2 (all bf16)
    int* bsrc = (int*)bufA;                        // NBUK*BCAP (dead before agg1)
    int* bdst = bsrc + NBUK * BCAP;                // NBUK*BCAP
    ushort* agg1o = (ushort*)bufA;                 // N*64 bf16
    ushort* agg2o = (ushort*)bufA;                 // N*128 bf16
    ushort* xs = (ushort*)bufB;                    // N*64 bf16
    ushort* hs = (ushort*)bufB;                    // N*128 bf16 (overwrites xs after agg1)
    ushort* h2 = (ushort*)bufB;                    // N*128 bf16 (overwrites hs after agg2)
    int* row_start = (int*)(bufB + (long long)N_NODES * HID);  // N+1
    float* dinv = (float*)(row_start + N_NODES + 1);  // N
    int* gcur = (int*)(dinv + N_NODES);            // NBUK
    int* bstart = gcur + NBUK;                     // NBUK
    int* gstart = bstart + NBUK;                   // N_GRAPHS+1
    int* csr = gstart + (N_GRAPHS + 1);            // E
    float* pooled = (float*)(csr + N_EDGES);       // G*HID

    // ----- CSR build (bucketed, wide blocks) -----
    hipMemsetAsync(gcur, 0, NBUK * sizeof(int), stream);
    hipMemsetAsync(pooled, 0, N_GRAPHS * HID * sizeof(float), stream);
    k_pass1<<<NBLK_P1, 1024, 0, stream>>>((const int4*)src, (const int4*)dst, gcur, bsrc, bdst);
    k_bscan<<<1, 512, 0, stream>>>(gcur, bstart, row_start);
    k_pass2<<<NBUK, 1024, 0, stream>>>(gcur, bstart, bsrc, bdst, x, row_start, dinv, csr, xs);
    k_gbound<<<(N_NODES + 255) / 256, 256, 0, stream>>>(batch, gstart);

    const int NGBLK = (N_NODES + 63) / 64;

    // ----- layer 1 -----
    k_agg1<<<N_NODES / 8, 256, 0, stream>>>(row_start, csr, (const uint32*)xs, dinv,
                                            (uint32*)agg1o);
    k_gemm_mfma<IN_DIM, 1><<<NGBLK, 256, 0, stream>>>(agg1o, W1, b1, dinv, hs);

    // ----- layer 2 -----
    k_agg2<<<N_NODES / 8, 256, 0, stream>>>(row_start, csr, (const uint2*)hs, dinv,
                                            (uint2*)agg2o);
    k_gemm_mfma<HID, 2><<<NGBLK, 256, 0, stream>>>(agg2o, W2, b2, dinv, h2);

    // ----- pool + head -----
    k_pool<<<N_GRAPHS * MAXCH, 256, 0, stream>>>((const uint32*)h2, gstart, pooled);
    k_head<<<1, 256, 0, stream>>>(pooled, gstart, Wfc, bfc, out);
}